// Round 10
// baseline (286.509 us; speedup 1.0000x reference)
//
#include <hip/hip_runtime.h>

typedef _Float16 f16;
typedef __attribute__((ext_vector_type(8))) _Float16 f16x8;
typedef __attribute__((ext_vector_type(4))) _Float16 f16x4;
typedef __attribute__((ext_vector_type(4))) float f32x4;
typedef unsigned int u32;

#define M2N 131072   // BATCH(4096) * Nc(32)
#define MFMA16 __builtin_amdgcn_mfma_f32_16x16x32_f16

struct C2 { float x, y; };
__device__ __forceinline__ C2 cmul(C2 a, C2 b){ C2 r; r.x = a.x*b.x - a.y*b.y; r.y = a.x*b.y + a.y*b.x; return r; }
__device__ __forceinline__ C2 cadd(C2 a, C2 b){ C2 r; r.x = a.x+b.x; r.y = a.y+b.y; return r; }
__device__ __forceinline__ C2 csub(C2 a, C2 b){ C2 r; r.x = a.x-b.x; r.y = a.y-b.y; return r; }
__device__ __forceinline__ C2 conjc(C2 a){ C2 r; r.x = a.x; r.y = -a.y; return r; }
__device__ __forceinline__ C2 cneg(C2 a){ C2 r; r.x = -a.x; r.y = -a.y; return r; }
__device__ __forceinline__ float cabs2(C2 a){ return a.x*a.x + a.y*a.y; }
__device__ __forceinline__ float dotr(C2 a, C2 b){ return a.x*b.x + a.y*b.y; }

__device__ __forceinline__ float wred(float v){
  #pragma unroll
  for (int s = 32; s > 0; s >>= 1) v += __shfl_xor(v, s, 64);
  return v;
}

// ---------------------------------------------------------------- prep
// Frag-linear hi/lo f16 weight fragments for 16x16x32 MFMA.
// Frag layout (both operands identical): lane l holds [idx0=l&15][k=(l>>4)*8+e].
__global__ void k_prep(const float* __restrict__ W0, const float* __restrict__ W1,
                       const float* __restrict__ W2, const float* __restrict__ W3,
                       f16* __restrict__ wfr12, f16* __restrict__ wfr0,
                       f16* __restrict__ wfr3, float* __restrict__ slots)
{
  const int b = blockIdx.x, tid = threadIdx.x;
  if (b < 64){
    const int slot = b*256 + tid;        // [0, 16384)
    const int lane = slot & 63;
    const int rest = slot >> 6;          // L*128 + nt*8 + kt
    const int kt = rest & 7, nt = (rest >> 3) & 15, L = rest >> 7;
    const float* W = L ? W2 : W1;
    const int n = nt*16 + (lane & 15);
    f16* dst = wfr12 + (size_t)rest*1024 + lane*8;
    #pragma unroll
    for (int e = 0; e < 8; ++e){
      const int k = kt*32 + (lane>>4)*8 + e;
      const float w = W[k*256 + n];
      const f16 h = (f16)w;
      dst[e] = h; dst[512+e] = (f16)(w - (float)h);
    }
  } else if (b == 64){
    for (int i = 0; i < 4; ++i){
      const int slot = i*256 + tid;      // [0,1024)
      const int lane = slot & 63, nt = slot >> 6;
      const int col = nt*16 + (lane & 15);
      f16* dst = wfr0 + (size_t)nt*1024 + lane*8;
      #pragma unroll
      for (int e = 0; e < 8; ++e){
        const int k = (lane>>4)*8 + e;
        const float w = (k < 8) ? W0[k*256 + col] : 0.f;
        const f16 h = (f16)w;
        dst[e] = h; dst[512+e] = (f16)(w - (float)h);
      }
    }
  } else {
    slots[tid] = 0.f;   // zero bisection accumulators (256 floats)
    for (int i = 0; i < 2; ++i){
      const int slot = i*256 + tid;      // [0,512)
      const int lane = slot & 63, kt = slot >> 6;
      const int col = lane & 15;
      f16* dst = wfr3 + (size_t)kt*1024 + lane*8;
      #pragma unroll
      for (int e = 0; e < 8; ++e){
        const int k = kt*32 + (lane>>4)*8 + e;
        const float w = (col < 8) ? W3[k*8 + col] : 0.f;
        const f16 h = (f16)w;
        dst[e] = h; dst[512+e] = (f16)(w - (float)h);
      }
    }
  }
}

// ---------------------------------------------------------------- F_RF + g2
__global__ void k_frf(const float* __restrict__ H, float2* __restrict__ frf,
                      float2* __restrict__ g2)
{
  const int b2 = blockIdx.x*2 + (threadIdx.x >> 7);
  const int tt = threadIdx.x & 127;
  const int t = tt >> 1, k = tt & 1;
  __shared__ float2 s[2][128];
  const size_t base = ((size_t)(b2*2 + k)*32 + 16)*128;
  const float are = H[base + t];
  const float aim = H[base];
  const float inv = rsqrtf(are*are + aim*aim) * 0.125f;
  float2 v; v.x = are*inv; v.y = -aim*inv;
  frf[((size_t)b2*64 + t)*2 + k] = v;
  s[threadIdx.x >> 7][tt] = v;
  __syncthreads();
  const int w = threadIdx.x >> 6;
  if ((w & 1) == 0){
    const int half = w >> 1;
    const int lane = threadIdx.x & 63;
    const float2 a = s[half][lane*2];
    const float2 b = s[half][lane*2 + 1];
    float re = a.x*b.x + a.y*b.y;          // a * conj(b)
    float im = a.y*b.x - a.x*b.y;
    re = wred(re); im = wred(im);
    if (lane == 0){ float2 g; g.x = re; g.y = im; g2[blockIdx.x*2 + half] = g; }
  }
}

// ---------------------------------------------------------------- H_equ -> x
__global__ void k_hequ(const float* __restrict__ H, const float2* __restrict__ frf,
                       float* __restrict__ x)
{
  const int m2 = blockIdx.x*4 + (threadIdx.x >> 6);
  const int lane = threadIdx.x & 63;
  const int n = m2 >> 12, b2 = m2 & 4095;
  const float4 f = *(const float4*)(frf + ((size_t)b2*64 + lane)*2);
  float accr[2][2], acci[2][2];
  #pragma unroll
  for (int i = 0; i < 2; ++i){
    const float* hr = H + (size_t)(n*8192 + b2*2 + i) * 128;
    const float re = hr[lane];
    const float im = hr[0];
    accr[i][0] = re*f.x - im*f.y;  acci[i][0] = re*f.y + im*f.x;
    accr[i][1] = re*f.z - im*f.w;  acci[i][1] = re*f.w + im*f.z;
  }
  #pragma unroll
  for (int i = 0; i < 2; ++i)
    #pragma unroll
    for (int j = 0; j < 2; ++j){ accr[i][j] = wred(accr[i][j]); acci[i][j] = wred(acci[i][j]); }
  if (lane == 0){
    float pw = 0.f;
    #pragma unroll
    for (int i = 0; i < 2; ++i)
      #pragma unroll
      for (int j = 0; j < 2; ++j) pw += accr[i][j]*accr[i][j] + acci[i][j]*acci[i][j];
    const float rs = rsqrtf(pw);
    *(float4*)(x + (size_t)m2*8)     = make_float4(accr[0][0]*rs, accr[0][1]*rs, accr[1][0]*rs, accr[1][1]*rs);
    *(float4*)(x + (size_t)m2*8 + 4) = make_float4(acci[0][0]*rs, acci[0][1]*rs, acci[1][0]*rs, acci[1][1]*rs);
  }
}

// ---------------------------------------------------------------- per-element algebra
struct Elem {
  C2 p[2][2], g[2][2], UW[2], d0, d1;
  float A0, A1, A2, c0, c1, c2, c3;
};
struct Coef { float A0, A1, A2, c0, c1, c2, c3; };

__device__ __forceinline__ void elem_core_v(float4 xr, float4 xi, float4 ya, float4 yb,
                                            Elem& E)
{
  C2 h[2][2];
  h[0][0].x = xr.x; h[0][0].y = xi.x; h[0][1].x = xr.y; h[0][1].y = xi.y;
  h[1][0].x = xr.z; h[1][0].y = xi.z; h[1][1].x = xr.w; h[1][1].y = xi.w;
  C2 U[2], Wm[2];
  U[0].x = ya.x; U[0].y = ya.z;  U[1].x = ya.y; U[1].y = ya.w;
  Wm[0].x = yb.x; Wm[0].y = yb.z; Wm[1].x = yb.y; Wm[1].y = yb.w;
  const float u20 = cabs2(U[0]), u21 = cabs2(U[1]);
  C2 cf[2];
  cf[0].x = Wm[0].x*u20; cf[0].y = Wm[0].y*u20;
  cf[1].x = Wm[1].x*u21; cf[1].y = Wm[1].y*u21;
  C2 B[2][2];
  #pragma unroll
  for (int i = 0; i < 2; ++i)
    #pragma unroll
    for (int j = 0; j < 2; ++j){
      const C2 t0 = cmul(conjc(h[0][i]), h[0][j]);
      const C2 t1 = cmul(conjc(h[1][i]), h[1][j]);
      B[i][j] = cadd(cmul(cf[0], t0), cmul(cf[1], t1));
    }
  C2 adj[2][2];
  adj[0][0] = B[1][1]; adj[0][1] = cneg(B[0][1]);
  adj[1][0] = cneg(B[1][0]); adj[1][1] = B[0][0];
  E.d0 = csub(cmul(B[0][0], B[1][1]), cmul(B[0][1], B[1][0]));
  E.d1.x = 2.f*(B[0][0].x + B[1][1].x);
  E.d1.y = 2.f*(B[0][0].y + B[1][1].y);
  #pragma unroll
  for (int k = 0; k < 2; ++k){
    #pragma unroll
    for (int j = 0; j < 2; ++j) E.g[k][j] = conjc(h[k][j]);
    #pragma unroll
    for (int i = 0; i < 2; ++i)
      E.p[k][i] = cadd(cmul(adj[i][0], E.g[k][0]), cmul(adj[i][1], E.g[k][1]));
    E.UW[k] = cmul(U[k], Wm[k]);
  }
  const float w0 = cabs2(E.UW[0]), w1 = cabs2(E.UW[1]);
  E.A0 = w0*(cabs2(E.p[0][0]) + cabs2(E.p[0][1])) + w1*(cabs2(E.p[1][0]) + cabs2(E.p[1][1]));
  E.A1 = 4.f*( w0*(dotr(E.p[0][0], E.g[0][0]) + dotr(E.p[0][1], E.g[0][1]))
             + w1*(dotr(E.p[1][0], E.g[1][0]) + dotr(E.p[1][1], E.g[1][1])) );
  E.A2 = 4.f*( w0*(cabs2(E.g[0][0]) + cabs2(E.g[0][1]))
             + w1*(cabs2(E.g[1][0]) + cabs2(E.g[1][1])) );
  E.c0 = cabs2(E.d0);
  E.c1 = 2.f*(E.d0.x*E.d1.x + E.d0.y*E.d1.y);
  E.c2 = cabs2(E.d1) + 8.f*E.d0.x;
  E.c3 = 8.f*E.d1.x;
}

__device__ __forceinline__ void elem_core(const float* __restrict__ x,
                                          const float* __restrict__ y,
                                          int gid, Elem& E)
{
  elem_core_v(*(const float4*)(x + (size_t)gid*8), *(const float4*)(x + (size_t)gid*8 + 4),
              *(const float4*)(y + (size_t)gid*8), *(const float4*)(y + (size_t)gid*8 + 4), E);
}

// ---------------------------------------------------------------- fused MLP (+coef)
// 48-row tiles (LDS 48KB -> 3 blocks/CU). Operand-swapped MFMA (acc = D[n][m]),
// two-plane f16 activations, 8-granule XOR swizzle, 2-deep B-register pipeline.
#define SWX(r, c) ((r)*256 + ((c) ^ (((r)&7)<<3)))

__launch_bounds__(256, 3)
__global__ void k_mlp(const float* __restrict__ x, const f16* __restrict__ wfr12,
                      const f16* __restrict__ wfr0, const f16* __restrict__ wfr3,
                      const float* __restrict__ bias0, const float* __restrict__ bias1,
                      const float* __restrict__ bias2, const float* __restrict__ bias3,
                      float* __restrict__ y, float* __restrict__ coef)
{
  __shared__ __align__(16) f16 xah[48*256];   // 24 KiB
  __shared__ __align__(16) f16 xal[48*256];   // 24 KiB
  const int tid = threadIdx.x, blk = blockIdx.x;
  const int lane = tid & 63, wv = tid >> 6;
  const int l15 = lane & 15, lh = lane >> 4;
  const int colb = wv*64;

  f32x4 acc[3][4];
  f16x8 ah[3], al[3];

  auto EPI = [&](){   // relu + exact f16 split + two-plane b64 swizzled writes
    #pragma unroll
    for (int Mt = 0; Mt < 3; ++Mt)
      #pragma unroll
      for (int nt = 0; nt < 4; ++nt){
        f16x4 h4, l4;
        #pragma unroll
        for (int r = 0; r < 4; ++r){
          const float v = fmaxf(acc[Mt][nt][r], 0.f);
          const f16 h = (f16)v;
          h4[r] = h; l4[r] = (f16)(v - (float)h);
        }
        const int idx = SWX(Mt*16 + l15, colb + nt*16 + lh*4);
        *(f16x4*)(xah + idx) = h4;
        *(f16x4*)(xal + idx) = l4;
      }
  };
  auto LDA = [&](int kt){
    #pragma unroll
    for (int Mt = 0; Mt < 3; ++Mt){
      const int idx = SWX(Mt*16 + l15, kt*32 + lh*8);
      ah[Mt] = *(const f16x8*)(xah + idx);
      al[Mt] = *(const f16x8*)(xal + idx);
    }
  };

  // ---------- layer 0 (8 -> 256, K padded to 32; zero-padded W kills garbage k)
  {
    f16x8 bh[4], bl[4];
    #pragma unroll
    for (int nt = 0; nt < 4; ++nt){
      const f32x4 b4 = *(const f32x4*)(bias0 + colb + nt*16 + lh*4);
      #pragma unroll
      for (int Mt = 0; Mt < 3; ++Mt) acc[Mt][nt] = b4;
    }
    #pragma unroll
    for (int Mt = 0; Mt < 3; ++Mt){
      const int row = blk*48 + Mt*16 + l15;   // tail rows read stale ws (finite), discarded
      const float* xr = x + (size_t)row*8;
      const float4 v0 = *(const float4*)xr;
      const float4 v1 = *(const float4*)(xr+4);
      const float vv[8] = {v0.x,v0.y,v0.z,v0.w,v1.x,v1.y,v1.z,v1.w};
      #pragma unroll
      for (int e = 0; e < 8; ++e){
        const f16 h = (f16)vv[e];
        ah[Mt][e] = h; al[Mt][e] = (f16)(vv[e] - (float)h);
      }
    }
    #pragma unroll
    for (int nt = 0; nt < 4; ++nt){
      bh[nt] = *(const f16x8*)(wfr0 + (size_t)(wv*4+nt)*1024 + lane*8);
      bl[nt] = *(const f16x8*)(wfr0 + (size_t)(wv*4+nt)*1024 + 512 + lane*8);
    }
    #pragma unroll
    for (int Mt = 0; Mt < 3; ++Mt)
      #pragma unroll
      for (int nt = 0; nt < 4; ++nt){
        acc[Mt][nt] = MFMA16(bh[nt], ah[Mt], acc[Mt][nt], 0, 0, 0);
        acc[Mt][nt] = MFMA16(bh[nt], al[Mt], acc[Mt][nt], 0, 0, 0);
        acc[Mt][nt] = MFMA16(bl[nt], ah[Mt], acc[Mt][nt], 0, 0, 0);
      }
    EPI();
  }
  __syncthreads();

  // ---------- layers 1,2 (256 -> 256), 2-deep B pipeline
  for (int L = 0; L < 2; ++L){
    const float* bs = L ? bias2 : bias1;
    const f16* wL = wfr12 + (size_t)L*131072;
    #pragma unroll
    for (int nt = 0; nt < 4; ++nt){
      const f32x4 b4 = *(const f32x4*)(bs + colb + nt*16 + lh*4);
      #pragma unroll
      for (int Mt = 0; Mt < 3; ++Mt) acc[Mt][nt] = b4;
    }
    f16x8 b0h[4], b0l[4], b1h[4], b1l[4];
    auto LDB0 = [&](int kt){
      #pragma unroll
      for (int nt = 0; nt < 4; ++nt){
        const size_t f = ((size_t)((wv*4+nt)*8 + kt))*1024;
        b0h[nt] = *(const f16x8*)(wL + f + lane*8);
        b0l[nt] = *(const f16x8*)(wL + f + 512 + lane*8);
      }
    };
    auto LDB1 = [&](int kt){
      #pragma unroll
      for (int nt = 0; nt < 4; ++nt){
        const size_t f = ((size_t)((wv*4+nt)*8 + kt))*1024;
        b1h[nt] = *(const f16x8*)(wL + f + lane*8);
        b1l[nt] = *(const f16x8*)(wL + f + 512 + lane*8);
      }
    };
    auto FMA0 = [&](){
      #pragma unroll
      for (int Mt = 0; Mt < 3; ++Mt)
        #pragma unroll
        for (int nt = 0; nt < 4; ++nt){
          acc[Mt][nt] = MFMA16(b0h[nt], ah[Mt], acc[Mt][nt], 0, 0, 0);
          acc[Mt][nt] = MFMA16(b0h[nt], al[Mt], acc[Mt][nt], 0, 0, 0);
          acc[Mt][nt] = MFMA16(b0l[nt], ah[Mt], acc[Mt][nt], 0, 0, 0);
        }
    };
    auto FMA1 = [&](){
      #pragma unroll
      for (int Mt = 0; Mt < 3; ++Mt)
        #pragma unroll
        for (int nt = 0; nt < 4; ++nt){
          acc[Mt][nt] = MFMA16(b1h[nt], ah[Mt], acc[Mt][nt], 0, 0, 0);
          acc[Mt][nt] = MFMA16(b1h[nt], al[Mt], acc[Mt][nt], 0, 0, 0);
          acc[Mt][nt] = MFMA16(b1l[nt], ah[Mt], acc[Mt][nt], 0, 0, 0);
        }
    };
    LDB0(0);
    #pragma unroll
    for (int kp = 0; kp < 4; ++kp){
      const int kt = kp*2;
      LDB1(kt + 1);
      LDA(kt);
      FMA0();
      if (kt + 2 < 8) LDB0(kt + 2);
      LDA(kt + 1);
      FMA1();
    }
    __syncthreads();   // all reads done before overwrite
    EPI();
    __syncthreads();
  }

  // ---------- layer 3 (256 -> 8, N padded to 16; zero-padded W cols), pipelined
  f32x4 a3[3];
  {
    f32x4 b4 = {0.f, 0.f, 0.f, 0.f};
    if (lh < 2) b4 = *(const f32x4*)(bias3 + lh*4);
    #pragma unroll
    for (int Mt = 0; Mt < 3; ++Mt) a3[Mt] = b4;
  }
  {
    f16x8 c0h, c0l, c1h, c1l;
    c0h = *(const f16x8*)(wfr3 + lane*8);
    c0l = *(const f16x8*)(wfr3 + 512 + lane*8);
    #pragma unroll
    for (int kp = 0; kp < 4; ++kp){
      const int kt = kp*2;
      c1h = *(const f16x8*)(wfr3 + (size_t)(kt+1)*1024 + lane*8);
      c1l = *(const f16x8*)(wfr3 + (size_t)(kt+1)*1024 + 512 + lane*8);
      LDA(kt);
      #pragma unroll
      for (int Mt = 0; Mt < 3; ++Mt){
        a3[Mt] = MFMA16(c0h, ah[Mt], a3[Mt], 0, 0, 0);
        a3[Mt] = MFMA16(c0h, al[Mt], a3[Mt], 0, 0, 0);
        a3[Mt] = MFMA16(c0l, ah[Mt], a3[Mt], 0, 0, 0);
      }
      if (kt + 2 < 8){
        c0h = *(const f16x8*)(wfr3 + (size_t)(kt+2)*1024 + lane*8);
        c0l = *(const f16x8*)(wfr3 + (size_t)(kt+2)*1024 + 512 + lane*8);
      }
      LDA(kt + 1);
      #pragma unroll
      for (int Mt = 0; Mt < 3; ++Mt){
        a3[Mt] = MFMA16(c1h, ah[Mt], a3[Mt], 0, 0, 0);
        a3[Mt] = MFMA16(c1h, al[Mt], a3[Mt], 0, 0, 0);
        a3[Mt] = MFMA16(c1l, ah[Mt], a3[Mt], 0, 0, 0);
      }
    }
  }
  if (lh < 2){
    #pragma unroll
    for (int Mt = 0; Mt < 3; ++Mt){
      const int row = blk*48 + Mt*16 + l15;
      if (row < M2N) *(f32x4*)(y + (size_t)row*8 + lh*4) = a3[Mt];
    }
  }

  // ---------- fused coef: exchange y rows via LDS, 48 threads run elem_core
  __syncthreads();   // all LDA reads of xah/xal done
  {
    float* yl = (float*)xal;
    if (lh < 2){
      #pragma unroll
      for (int Mt = 0; Mt < 3; ++Mt)
        *(f32x4*)(yl + (Mt*16 + l15)*8 + lh*4) = a3[Mt];
    }
  }
  __syncthreads();
  if (tid < 48){
    const int row = blk*48 + tid;
    if (row < M2N){
      const float* yl = (const float*)xal;
      const float4 xr = *(const float4*)(x + (size_t)row*8);
      const float4 xi = *(const float4*)(x + (size_t)row*8 + 4);
      const float4 ya = *(const float4*)(yl + tid*8);
      const float4 yb = *(const float4*)(yl + tid*8 + 4);
      Elem E;
      elem_core_v(xr, xi, ya, yb, E);
      *(float4*)(coef + (size_t)row*8)     = make_float4(E.A0, E.A1, E.A2, E.c0);
      *(float4*)(coef + (size_t)row*8 + 4) = make_float4(E.c1, E.c2, E.c3, 0.f);
    }
  }
}

// ---------------------------------------------------------------- bisection machinery
__device__ __forceinline__ float evalf(float mu, const Coef& C){
  const float num = C.A0 + mu*(C.A1 + mu*C.A2);
  const float den = C.c0 + mu*(C.c1 + mu*(C.c2 + mu*(C.c3 + mu*16.f)));
  return num/den;
}

// Replay nrounds of multi-level bisection decisions from slot sums.
__device__ __forceinline__ void replay(const float* __restrict__ slots, int nrounds,
                                       float& lo, float& hi)
{
  const int DP[4] = {5, 5, 5, 4};
  for (int r = 0; r < nrounds; ++r){
    const float lo0 = lo, span = hi - lo;
    int k = 0;
    for (int d = 0; d < DP[r]; ++d){
      const float sd = span * (1.0f / (float)(1 << (d+1)));
      const float mu = fmaf((float)(2*k + 1), sd, lo0);
      const bool big = slots[r*32 + (1 << d) - 1 + k] > 1.0f;
      lo = big ? mu : lo;
      hi = big ? hi : mu;
      k = 2*k + (big ? 1 : 0);
    }
  }
}

// Replay prior rounds, evaluate this round's full depth-D candidate subtree,
// block-reduce, one atomicAdd per candidate into slots[ROUND*32 + node].
template<int ROUND, int D>
__global__ void k_red(const float* __restrict__ coef, float* __restrict__ slots)
{
  const int tid = threadIdx.x;
  const int gid = blockIdx.x*256 + tid;
  const int lane = tid & 63, wv = tid >> 6;
  __shared__ float r4[4][32];

  const float4 a = *(const float4*)(coef + (size_t)gid*8);
  const float4 b = *(const float4*)(coef + (size_t)gid*8 + 4);
  Coef C; C.A0 = a.x; C.A1 = a.y; C.A2 = a.z; C.c0 = a.w;
  C.c1 = b.x; C.c2 = b.y; C.c3 = b.z;

  float lo = 0.f, hi = 10.f;
  replay(slots, ROUND, lo, hi);

  const float lo0 = lo, span = hi - lo;
  int node = 0;
  #pragma unroll
  for (int d = 0; d < D; ++d){
    const float sd = span * (1.0f / (float)(1 << (d+1)));
    for (int k = 0; k < (1 << d); ++k){
      const float mu = fmaf((float)(2*k + 1), sd, lo0);
      const float f = wred(evalf(mu, C));
      if (lane == 0) r4[wv][node] = f;
      ++node;
    }
  }
  __syncthreads();
  if (tid < (1 << D) - 1)
    atomicAdd(&slots[ROUND*32 + tid], r4[0][tid] + r4[1][tid] + r4[2][tid] + r4[3][tid]);
}

// ---------------------------------------------------------------- output (+final V,Pm)
// Per b2-block: threads 0..31 compute V at gid=n*4096+b2; threads 32..63 compute
// the (quirky) power normalizer at gid=b2*32+n. Then 256 threads do F_RF @ V.
__global__ void k_out(const float2* __restrict__ frf, const float* __restrict__ x,
                      const float* __restrict__ y, const float2* __restrict__ g2,
                      const float* __restrict__ slots, float* __restrict__ out)
{
  const int b2 = blockIdx.x;
  const int tid = threadIdx.x;
  __shared__ float Vs[32][8];
  __shared__ float scs[32];

  if (tid < 64){
    const int n = tid & 31;
    const bool isP = tid >= 32;
    const int gid = isP ? (b2*32 + n) : (n*4096 + b2);
    float lo = 0.f, hi = 10.f;
    replay(slots, 4, lo, hi);
    const float mu = 0.5f*(lo + hi);   // 20th midpoint
    Elem E;
    elem_core(x, y, gid, E);
    C2 det; det.x = E.d0.x + mu*E.d1.x + 4.f*mu*mu; det.y = E.d0.y + mu*E.d1.y;
    const float id = 1.f/cabs2(det);
    C2 idet; idet.x = det.x*id; idet.y = -det.y*id;
    C2 Vv[2][2];
    #pragma unroll
    for (int k = 0; k < 2; ++k)
      #pragma unroll
      for (int i = 0; i < 2; ++i){
        C2 t; t.x = E.p[k][i].x + 2.f*mu*E.g[k][i].x; t.y = E.p[k][i].y + 2.f*mu*E.g[k][i].y;
        Vv[i][k] = cmul(E.UW[k], cmul(t, idet));
      }
    if (!isP){
      Vs[n][0] = Vv[0][0].x; Vs[n][1] = Vv[0][0].y;
      Vs[n][2] = Vv[0][1].x; Vs[n][3] = Vv[0][1].y;
      Vs[n][4] = Vv[1][0].x; Vs[n][5] = Vv[1][0].y;
      Vs[n][6] = Vv[1][1].x; Vs[n][7] = Vv[1][1].y;
    } else {
      const float2 gg2 = g2[gid & 4095];
      C2 gc; gc.x = gg2.x; gc.y = gg2.y;
      float P = 0.f;
      #pragma unroll
      for (int k = 0; k < 2; ++k){
        const C2 a = Vv[0][k], b = Vv[1][k];
        P += cabs2(a) + cabs2(b);
        const C2 t = cmul(gc, cmul(a, conjc(b)));
        P += 2.f*t.x;
      }
      scs[n] = 1.41421356237f * rsqrtf(P);
    }
  }
  __syncthreads();

  const int t = tid & 63;
  const int ng = tid >> 6;
  const float4 f = *(const float4*)(frf + ((size_t)b2*64 + t)*2);
  C2 f0, f1; f0.x = f.x; f0.y = f.y; f1.x = f.z; f1.y = f.w;
  for (int n = ng; n < 32; n += 4){
    C2 M00, M01, M10, M11;
    M00.x = Vs[n][0]; M00.y = Vs[n][1]; M01.x = Vs[n][2]; M01.y = Vs[n][3];
    M10.x = Vs[n][4]; M10.y = Vs[n][5]; M11.x = Vs[n][6]; M11.y = Vs[n][7];
    const float sc = scs[n];
    const C2 c0 = cadd(cmul(f0, M00), cmul(f1, M10));
    const C2 c1 = cadd(cmul(f0, M01), cmul(f1, M11));
    const size_t base = (size_t)b2*8192 + n*128 + t*2;
    *(float2*)(out + base)        = make_float2(c0.x*sc, c1.x*sc);
    *(float2*)(out + base + 4096) = make_float2(c0.y*sc, c1.y*sc);
  }
}

// ---------------------------------------------------------------- launch
extern "C" void kernel_launch(void* const* d_in, const int* in_sizes, int n_in,
                              void* d_out, int out_size, void* d_ws, size_t ws_size,
                              hipStream_t stream)
{
  const float* H  = (const float*)d_in[0];
  const float* W0 = (const float*)d_in[1];
  const float* b0 = (const float*)d_in[2];
  const float* W1 = (const float*)d_in[3];
  const float* b1 = (const float*)d_in[4];
  const float* W2 = (const float*)d_in[5];
  const float* b2 = (const float*)d_in[6];
  const float* W3 = (const float*)d_in[7];
  const float* b3 = (const float*)d_in[8];
  float* out = (float*)d_out;
  char* ws = (char*)d_ws;
  (void)in_sizes; (void)n_in; (void)out_size; (void)ws_size;

  size_t o = 0;
  auto alloc = [&](size_t bytes) -> void* {
    void* p = ws + o;
    o += (bytes + 255) & ~(size_t)255;
    return p;
  };
  float2* frf   = (float2*)alloc((size_t)4096*64*2*sizeof(float2)); // 4 MiB
  float2* g2    = (float2*)alloc((size_t)4096*sizeof(float2));
  float*  xbuf  = (float*) alloc((size_t)M2N*8*sizeof(float));      // 4 MiB
  float*  ybuf  = (float*) alloc((size_t)M2N*8*sizeof(float));      // 4 MiB
  float*  coef  = (float*) alloc((size_t)M2N*8*sizeof(float));      // 4 MiB
  float*  slots = (float*) alloc(256*sizeof(float));                // 1 KiB
  f16*    wfr12 = (f16*)   alloc((size_t)256*1024*sizeof(f16));     // 512 KiB
  f16*    wfr0  = (f16*)   alloc((size_t)16*1024*sizeof(f16));      // 32 KiB
  f16*    wfr3  = (f16*)   alloc((size_t)8*1024*sizeof(f16));       // 16 KiB

  k_prep<<<66, 256, 0, stream>>>(W0, W1, W2, W3, wfr12, wfr0, wfr3, slots);
  k_frf<<<2048, 256, 0, stream>>>(H, frf, g2);
  k_hequ<<<32768, 256, 0, stream>>>(H, frf, xbuf);
  k_mlp<<<2731, 256, 0, stream>>>(xbuf, wfr12, wfr0, wfr3, b0, b1, b2, b3, ybuf, coef);
  k_red<0,5><<<512, 256, 0, stream>>>(coef, slots);
  k_red<1,5><<<512, 256, 0, stream>>>(coef, slots);
  k_red<2,5><<<512, 256, 0, stream>>>(coef, slots);
  k_red<3,4><<<512, 256, 0, stream>>>(coef, slots);
  k_out<<<4096, 256, 0, stream>>>(frf, xbuf, ybuf, g2, slots, out);
}

// Round 11
// 277.305 us; speedup vs baseline: 1.0332x; 1.0332x over previous
//
#include <hip/hip_runtime.h>

typedef _Float16 f16;
typedef __attribute__((ext_vector_type(8))) _Float16 f16x8;
typedef __attribute__((ext_vector_type(4))) _Float16 f16x4;
typedef __attribute__((ext_vector_type(4))) float f32x4;
typedef unsigned int u32;

#define M2N 131072   // BATCH(4096) * Nc(32)
#define MFMA16 __builtin_amdgcn_mfma_f32_16x16x32_f16

struct C2 { float x, y; };
__device__ __forceinline__ C2 cmul(C2 a, C2 b){ C2 r; r.x = a.x*b.x - a.y*b.y; r.y = a.x*b.y + a.y*b.x; return r; }
__device__ __forceinline__ C2 cadd(C2 a, C2 b){ C2 r; r.x = a.x+b.x; r.y = a.y+b.y; return r; }
__device__ __forceinline__ C2 csub(C2 a, C2 b){ C2 r; r.x = a.x-b.x; r.y = a.y-b.y; return r; }
__device__ __forceinline__ C2 conjc(C2 a){ C2 r; r.x = a.x; r.y = -a.y; return r; }
__device__ __forceinline__ C2 cneg(C2 a){ C2 r; r.x = -a.x; r.y = -a.y; return r; }
__device__ __forceinline__ float cabs2(C2 a){ return a.x*a.x + a.y*a.y; }
__device__ __forceinline__ float dotr(C2 a, C2 b){ return a.x*b.x + a.y*b.y; }

__device__ __forceinline__ float wred(float v){
  #pragma unroll
  for (int s = 32; s > 0; s >>= 1) v += __shfl_xor(v, s, 64);
  return v;
}

// ---------------------------------------------------------------- prep
// Frag-linear hi/lo f16 weight fragments for 16x16x32 MFMA.
// Frag layout (both operands identical): lane l holds [idx0=l&15][k=(l>>4)*8+e].
__global__ void k_prep(const float* __restrict__ W0, const float* __restrict__ W1,
                       const float* __restrict__ W2, const float* __restrict__ W3,
                       f16* __restrict__ wfr12, f16* __restrict__ wfr0,
                       f16* __restrict__ wfr3, float* __restrict__ slots)
{
  const int b = blockIdx.x, tid = threadIdx.x;
  if (b < 64){
    const int slot = b*256 + tid;        // [0, 16384)
    const int lane = slot & 63;
    const int rest = slot >> 6;          // L*128 + nt*8 + kt
    const int kt = rest & 7, nt = (rest >> 3) & 15, L = rest >> 7;
    const float* W = L ? W2 : W1;
    const int n = nt*16 + (lane & 15);
    f16* dst = wfr12 + (size_t)rest*1024 + lane*8;
    #pragma unroll
    for (int e = 0; e < 8; ++e){
      const int k = kt*32 + (lane>>4)*8 + e;
      const float w = W[k*256 + n];
      const f16 h = (f16)w;
      dst[e] = h; dst[512+e] = (f16)(w - (float)h);
    }
  } else if (b == 64){
    for (int i = 0; i < 4; ++i){
      const int slot = i*256 + tid;      // [0,1024)
      const int lane = slot & 63, nt = slot >> 6;
      const int col = nt*16 + (lane & 15);
      f16* dst = wfr0 + (size_t)nt*1024 + lane*8;
      #pragma unroll
      for (int e = 0; e < 8; ++e){
        const int k = (lane>>4)*8 + e;
        const float w = (k < 8) ? W0[k*256 + col] : 0.f;
        const f16 h = (f16)w;
        dst[e] = h; dst[512+e] = (f16)(w - (float)h);
      }
    }
  } else {
    slots[tid] = 0.f;   // zero bisection accumulators (256 floats)
    for (int i = 0; i < 2; ++i){
      const int slot = i*256 + tid;      // [0,512)
      const int lane = slot & 63, kt = slot >> 6;
      const int col = lane & 15;
      f16* dst = wfr3 + (size_t)kt*1024 + lane*8;
      #pragma unroll
      for (int e = 0; e < 8; ++e){
        const int k = kt*32 + (lane>>4)*8 + e;
        const float w = (col < 8) ? W3[k*8 + col] : 0.f;
        const f16 h = (f16)w;
        dst[e] = h; dst[512+e] = (f16)(w - (float)h);
      }
    }
  }
}

// ---------------------------------------------------------------- F_RF + g2
__global__ void k_frf(const float* __restrict__ H, float2* __restrict__ frf,
                      float2* __restrict__ g2)
{
  const int b2 = blockIdx.x*2 + (threadIdx.x >> 7);
  const int tt = threadIdx.x & 127;
  const int t = tt >> 1, k = tt & 1;
  __shared__ float2 s[2][128];
  const size_t base = ((size_t)(b2*2 + k)*32 + 16)*128;
  const float are = H[base + t];
  const float aim = H[base];
  const float inv = rsqrtf(are*are + aim*aim) * 0.125f;
  float2 v; v.x = are*inv; v.y = -aim*inv;
  frf[((size_t)b2*64 + t)*2 + k] = v;
  s[threadIdx.x >> 7][tt] = v;
  __syncthreads();
  const int w = threadIdx.x >> 6;
  if ((w & 1) == 0){
    const int half = w >> 1;
    const int lane = threadIdx.x & 63;
    const float2 a = s[half][lane*2];
    const float2 b = s[half][lane*2 + 1];
    float re = a.x*b.x + a.y*b.y;          // a * conj(b)
    float im = a.y*b.x - a.x*b.y;
    re = wred(re); im = wred(im);
    if (lane == 0){ float2 g; g.x = re; g.y = im; g2[blockIdx.x*2 + half] = g; }
  }
}

// ---------------------------------------------------------------- H_equ -> x
__global__ void k_hequ(const float* __restrict__ H, const float2* __restrict__ frf,
                       float* __restrict__ x)
{
  const int m2 = blockIdx.x*4 + (threadIdx.x >> 6);
  const int lane = threadIdx.x & 63;
  const int n = m2 >> 12, b2 = m2 & 4095;
  const float4 f = *(const float4*)(frf + ((size_t)b2*64 + lane)*2);
  float accr[2][2], acci[2][2];
  #pragma unroll
  for (int i = 0; i < 2; ++i){
    const float* hr = H + (size_t)(n*8192 + b2*2 + i) * 128;
    const float re = hr[lane];
    const float im = hr[0];
    accr[i][0] = re*f.x - im*f.y;  acci[i][0] = re*f.y + im*f.x;
    accr[i][1] = re*f.z - im*f.w;  acci[i][1] = re*f.w + im*f.z;
  }
  #pragma unroll
  for (int i = 0; i < 2; ++i)
    #pragma unroll
    for (int j = 0; j < 2; ++j){ accr[i][j] = wred(accr[i][j]); acci[i][j] = wred(acci[i][j]); }
  if (lane == 0){
    float pw = 0.f;
    #pragma unroll
    for (int i = 0; i < 2; ++i)
      #pragma unroll
      for (int j = 0; j < 2; ++j) pw += accr[i][j]*accr[i][j] + acci[i][j]*acci[i][j];
    const float rs = rsqrtf(pw);
    *(float4*)(x + (size_t)m2*8)     = make_float4(accr[0][0]*rs, accr[0][1]*rs, accr[1][0]*rs, accr[1][1]*rs);
    *(float4*)(x + (size_t)m2*8 + 4) = make_float4(acci[0][0]*rs, acci[0][1]*rs, acci[1][0]*rs, acci[1][1]*rs);
  }
}

// ---------------------------------------------------------------- fused MLP
// 48-row tiles (LDS 48KB -> 3 blocks/CU). Operand-swapped MFMA (acc = D[n][m]),
// two-plane f16 activations, 8-granule XOR swizzle.
// NOTE (r10 post-mortem): manual 2-deep B-register pipelining + fused elem_core
// tail caused scratch spills (WRITE_SIZE 4->35 MB, MfmaUtil 53->42). Keep this
// version register-lean (72 VGPR): the #pragma unroll 2 + 3 waves/SIMD TLP is
// the best measured config (106 us, MfmaUtil 53%).
#define SWX(r, c) ((r)*256 + ((c) ^ (((r)&7)<<3)))

__launch_bounds__(256, 3)
__global__ void k_mlp(const float* __restrict__ x, const f16* __restrict__ wfr12,
                      const f16* __restrict__ wfr0, const f16* __restrict__ wfr3,
                      const float* __restrict__ bias0, const float* __restrict__ bias1,
                      const float* __restrict__ bias2, const float* __restrict__ bias3,
                      float* __restrict__ y)
{
  __shared__ __align__(16) f16 xah[48*256];   // 24 KiB
  __shared__ __align__(16) f16 xal[48*256];   // 24 KiB
  const int tid = threadIdx.x, blk = blockIdx.x;
  const int lane = tid & 63, wv = tid >> 6;
  const int l15 = lane & 15, lh = lane >> 4;
  const int colb = wv*64;

  f32x4 acc[3][4];
  f16x8 ah[3], al[3], bh[4], bl[4];

  auto EPI = [&](){   // relu + exact f16 split + two-plane b64 swizzled writes
    #pragma unroll
    for (int Mt = 0; Mt < 3; ++Mt)
      #pragma unroll
      for (int nt = 0; nt < 4; ++nt){
        f16x4 h4, l4;
        #pragma unroll
        for (int r = 0; r < 4; ++r){
          const float v = fmaxf(acc[Mt][nt][r], 0.f);
          const f16 h = (f16)v;
          h4[r] = h; l4[r] = (f16)(v - (float)h);
        }
        const int idx = SWX(Mt*16 + l15, colb + nt*16 + lh*4);
        *(f16x4*)(xah + idx) = h4;
        *(f16x4*)(xal + idx) = l4;
      }
  };

  // ---------- layer 0 (8 -> 256, K padded to 32; zero-padded W kills garbage k)
  #pragma unroll
  for (int nt = 0; nt < 4; ++nt){
    const f32x4 b4 = *(const f32x4*)(bias0 + colb + nt*16 + lh*4);
    #pragma unroll
    for (int Mt = 0; Mt < 3; ++Mt) acc[Mt][nt] = b4;
  }
  #pragma unroll
  for (int Mt = 0; Mt < 3; ++Mt){
    const int row = blk*48 + Mt*16 + l15;   // tail rows read stale ws (finite), discarded
    const float* xr = x + (size_t)row*8;
    const float4 v0 = *(const float4*)xr;
    const float4 v1 = *(const float4*)(xr+4);
    const float vv[8] = {v0.x,v0.y,v0.z,v0.w,v1.x,v1.y,v1.z,v1.w};
    #pragma unroll
    for (int e = 0; e < 8; ++e){
      const f16 h = (f16)vv[e];
      ah[Mt][e] = h; al[Mt][e] = (f16)(vv[e] - (float)h);
    }
  }
  #pragma unroll
  for (int nt = 0; nt < 4; ++nt){
    bh[nt] = *(const f16x8*)(wfr0 + (size_t)(wv*4+nt)*1024 + lane*8);
    bl[nt] = *(const f16x8*)(wfr0 + (size_t)(wv*4+nt)*1024 + 512 + lane*8);
  }
  #pragma unroll
  for (int Mt = 0; Mt < 3; ++Mt)
    #pragma unroll
    for (int nt = 0; nt < 4; ++nt){
      acc[Mt][nt] = MFMA16(bh[nt], ah[Mt], acc[Mt][nt], 0, 0, 0);
      acc[Mt][nt] = MFMA16(bh[nt], al[Mt], acc[Mt][nt], 0, 0, 0);
      acc[Mt][nt] = MFMA16(bl[nt], ah[Mt], acc[Mt][nt], 0, 0, 0);
    }
  EPI();
  __syncthreads();

  // ---------- layers 1,2 (256 -> 256)
  for (int L = 0; L < 2; ++L){
    const float* bs = L ? bias2 : bias1;
    #pragma unroll
    for (int nt = 0; nt < 4; ++nt){
      const f32x4 b4 = *(const f32x4*)(bs + colb + nt*16 + lh*4);
      #pragma unroll
      for (int Mt = 0; Mt < 3; ++Mt) acc[Mt][nt] = b4;
    }
    #pragma unroll 2
    for (int kt = 0; kt < 8; ++kt){
      #pragma unroll
      for (int Mt = 0; Mt < 3; ++Mt){
        const int idx = SWX(Mt*16 + l15, kt*32 + lh*8);
        ah[Mt] = *(const f16x8*)(xah + idx);
        al[Mt] = *(const f16x8*)(xal + idx);
      }
      #pragma unroll
      for (int nt = 0; nt < 4; ++nt){
        const size_t f = ((size_t)(L*128 + (wv*4+nt)*8 + kt))*1024;
        bh[nt] = *(const f16x8*)(wfr12 + f + lane*8);
        bl[nt] = *(const f16x8*)(wfr12 + f + 512 + lane*8);
      }
      #pragma unroll
      for (int Mt = 0; Mt < 3; ++Mt)
        #pragma unroll
        for (int nt = 0; nt < 4; ++nt){
          acc[Mt][nt] = MFMA16(bh[nt], ah[Mt], acc[Mt][nt], 0, 0, 0);
          acc[Mt][nt] = MFMA16(bh[nt], al[Mt], acc[Mt][nt], 0, 0, 0);
          acc[Mt][nt] = MFMA16(bl[nt], ah[Mt], acc[Mt][nt], 0, 0, 0);
        }
    }
    __syncthreads();   // all reads done before overwrite
    EPI();
    __syncthreads();
  }

  // ---------- layer 3 (256 -> 8, N padded to 16; zero-padded W cols)
  f32x4 a3[3];
  {
    f32x4 b4 = {0.f, 0.f, 0.f, 0.f};
    if (lh < 2) b4 = *(const f32x4*)(bias3 + lh*4);
    #pragma unroll
    for (int Mt = 0; Mt < 3; ++Mt) a3[Mt] = b4;
  }
  #pragma unroll 2
  for (int kt = 0; kt < 8; ++kt){
    #pragma unroll
    for (int Mt = 0; Mt < 3; ++Mt){
      const int idx = SWX(Mt*16 + l15, kt*32 + lh*8);
      ah[Mt] = *(const f16x8*)(xah + idx);
      al[Mt] = *(const f16x8*)(xal + idx);
    }
    const f16x8 b3h = *(const f16x8*)(wfr3 + (size_t)kt*1024 + lane*8);
    const f16x8 b3l = *(const f16x8*)(wfr3 + (size_t)kt*1024 + 512 + lane*8);
    #pragma unroll
    for (int Mt = 0; Mt < 3; ++Mt){
      a3[Mt] = MFMA16(b3h, ah[Mt], a3[Mt], 0, 0, 0);
      a3[Mt] = MFMA16(b3h, al[Mt], a3[Mt], 0, 0, 0);
      a3[Mt] = MFMA16(b3l, ah[Mt], a3[Mt], 0, 0, 0);
    }
  }
  if (lh < 2){
    #pragma unroll
    for (int Mt = 0; Mt < 3; ++Mt){
      const int row = blk*48 + Mt*16 + l15;
      if (row < M2N) *(f32x4*)(y + (size_t)row*8 + lh*4) = a3[Mt];
    }
  }
}

// ---------------------------------------------------------------- per-element algebra
struct Elem {
  C2 p[2][2], g[2][2], UW[2], d0, d1;
  float A0, A1, A2, c0, c1, c2, c3;
};
struct Coef { float A0, A1, A2, c0, c1, c2, c3; };

__device__ __forceinline__ void elem_core(const float* __restrict__ x,
                                          const float* __restrict__ y,
                                          int gid, Elem& E)
{
  const float4 xr = *(const float4*)(x + (size_t)gid*8);
  const float4 xi = *(const float4*)(x + (size_t)gid*8 + 4);
  C2 h[2][2];
  h[0][0].x = xr.x; h[0][0].y = xi.x; h[0][1].x = xr.y; h[0][1].y = xi.y;
  h[1][0].x = xr.z; h[1][0].y = xi.z; h[1][1].x = xr.w; h[1][1].y = xi.w;
  const float4 ya = *(const float4*)(y + (size_t)gid*8);
  const float4 yb = *(const float4*)(y + (size_t)gid*8 + 4);
  C2 U[2], Wm[2];
  U[0].x = ya.x; U[0].y = ya.z;  U[1].x = ya.y; U[1].y = ya.w;
  Wm[0].x = yb.x; Wm[0].y = yb.z; Wm[1].x = yb.y; Wm[1].y = yb.w;
  const float u20 = cabs2(U[0]), u21 = cabs2(U[1]);
  C2 cf[2];
  cf[0].x = Wm[0].x*u20; cf[0].y = Wm[0].y*u20;
  cf[1].x = Wm[1].x*u21; cf[1].y = Wm[1].y*u21;
  C2 B[2][2];
  #pragma unroll
  for (int i = 0; i < 2; ++i)
    #pragma unroll
    for (int j = 0; j < 2; ++j){
      const C2 t0 = cmul(conjc(h[0][i]), h[0][j]);
      const C2 t1 = cmul(conjc(h[1][i]), h[1][j]);
      B[i][j] = cadd(cmul(cf[0], t0), cmul(cf[1], t1));
    }
  C2 adj[2][2];
  adj[0][0] = B[1][1]; adj[0][1] = cneg(B[0][1]);
  adj[1][0] = cneg(B[1][0]); adj[1][1] = B[0][0];
  E.d0 = csub(cmul(B[0][0], B[1][1]), cmul(B[0][1], B[1][0]));
  E.d1.x = 2.f*(B[0][0].x + B[1][1].x);
  E.d1.y = 2.f*(B[0][0].y + B[1][1].y);
  #pragma unroll
  for (int k = 0; k < 2; ++k){
    #pragma unroll
    for (int j = 0; j < 2; ++j) E.g[k][j] = conjc(h[k][j]);
    #pragma unroll
    for (int i = 0; i < 2; ++i)
      E.p[k][i] = cadd(cmul(adj[i][0], E.g[k][0]), cmul(adj[i][1], E.g[k][1]));
    E.UW[k] = cmul(U[k], Wm[k]);
  }
  const float w0 = cabs2(E.UW[0]), w1 = cabs2(E.UW[1]);
  E.A0 = w0*(cabs2(E.p[0][0]) + cabs2(E.p[0][1])) + w1*(cabs2(E.p[1][0]) + cabs2(E.p[1][1]));
  E.A1 = 4.f*( w0*(dotr(E.p[0][0], E.g[0][0]) + dotr(E.p[0][1], E.g[0][1]))
             + w1*(dotr(E.p[1][0], E.g[1][0]) + dotr(E.p[1][1], E.g[1][1])) );
  E.A2 = 4.f*( w0*(cabs2(E.g[0][0]) + cabs2(E.g[0][1]))
             + w1*(cabs2(E.g[1][0]) + cabs2(E.g[1][1])) );
  E.c0 = cabs2(E.d0);
  E.c1 = 2.f*(E.d0.x*E.d1.x + E.d0.y*E.d1.y);
  E.c2 = cabs2(E.d1) + 8.f*E.d0.x;
  E.c3 = 8.f*E.d1.x;
}

// ---------------------------------------------------------------- bisection machinery
__device__ __forceinline__ float evalf(float mu, const Coef& C){
  const float num = C.A0 + mu*(C.A1 + mu*C.A2);
  const float den = C.c0 + mu*(C.c1 + mu*(C.c2 + mu*(C.c3 + mu*16.f)));
  return num/den;
}

// Replay nrounds of multi-level bisection decisions from slot sums.
// Candidates mu(d,k) = lo0 + span*(2k+1)/2^(d+1), closed form; identical
// expressions in eval and replay -> internally consistent.
__device__ __forceinline__ void replay(const float* __restrict__ slots, int nrounds,
                                       float& lo, float& hi)
{
  const int DP[4] = {5, 5, 5, 4};
  for (int r = 0; r < nrounds; ++r){
    const float lo0 = lo, span = hi - lo;
    int k = 0;
    for (int d = 0; d < DP[r]; ++d){
      const float sd = span * (1.0f / (float)(1 << (d+1)));
      const float mu = fmaf((float)(2*k + 1), sd, lo0);
      const bool big = slots[r*32 + (1 << d) - 1 + k] > 1.0f;
      lo = big ? mu : lo;
      hi = big ? hi : mu;
      k = 2*k + (big ? 1 : 0);
    }
  }
}

// ---------------------------------------------------------------- coef
__global__ void k_coef(const float* __restrict__ x, const float* __restrict__ y,
                       float* __restrict__ coef)
{
  const int gid = blockIdx.x*256 + threadIdx.x;
  Elem E;
  elem_core(x, y, gid, E);
  *(float4*)(coef + (size_t)gid*8)     = make_float4(E.A0, E.A1, E.A2, E.c0);
  *(float4*)(coef + (size_t)gid*8 + 4) = make_float4(E.c1, E.c2, E.c3, 0.f);
}

// ---------------------------------------------------------------- bisection round
// Replay prior rounds, evaluate this round's full depth-D candidate subtree,
// block-reduce, one atomicAdd per candidate into slots[ROUND*32 + node].
template<int ROUND, int D>
__global__ void k_red(const float* __restrict__ coef, float* __restrict__ slots)
{
  const int tid = threadIdx.x;
  const int gid = blockIdx.x*256 + tid;
  const int lane = tid & 63, wv = tid >> 6;
  __shared__ float r4[4][32];

  const float4 a = *(const float4*)(coef + (size_t)gid*8);
  const float4 b = *(const float4*)(coef + (size_t)gid*8 + 4);
  Coef C; C.A0 = a.x; C.A1 = a.y; C.A2 = a.z; C.c0 = a.w;
  C.c1 = b.x; C.c2 = b.y; C.c3 = b.z;

  float lo = 0.f, hi = 10.f;
  replay(slots, ROUND, lo, hi);

  const float lo0 = lo, span = hi - lo;
  int node = 0;
  #pragma unroll
  for (int d = 0; d < D; ++d){
    const float sd = span * (1.0f / (float)(1 << (d+1)));
    for (int k = 0; k < (1 << d); ++k){
      const float mu = fmaf((float)(2*k + 1), sd, lo0);
      const float f = wred(evalf(mu, C));
      if (lane == 0) r4[wv][node] = f;
      ++node;
    }
  }
  __syncthreads();
  if (tid < (1 << D) - 1)
    atomicAdd(&slots[ROUND*32 + tid], r4[0][tid] + r4[1][tid] + r4[2][tid] + r4[3][tid]);
}

// ---------------------------------------------------------------- output (+final V,Pm)
// Per b2-block: threads 0..31 compute V at gid=n*4096+b2; threads 32..63 compute
// the (quirky) power normalizer at gid=b2*32+n. Then 256 threads do F_RF @ V.
__global__ void k_out(const float2* __restrict__ frf, const float* __restrict__ x,
                      const float* __restrict__ y, const float2* __restrict__ g2,
                      const float* __restrict__ slots, float* __restrict__ out)
{
  const int b2 = blockIdx.x;
  const int tid = threadIdx.x;
  __shared__ float Vs[32][8];
  __shared__ float scs[32];

  if (tid < 64){
    const int n = tid & 31;
    const bool isP = tid >= 32;
    const int gid = isP ? (b2*32 + n) : (n*4096 + b2);
    float lo = 0.f, hi = 10.f;
    replay(slots, 4, lo, hi);
    const float mu = 0.5f*(lo + hi);   // 20th midpoint
    Elem E;
    elem_core(x, y, gid, E);
    C2 det; det.x = E.d0.x + mu*E.d1.x + 4.f*mu*mu; det.y = E.d0.y + mu*E.d1.y;
    const float id = 1.f/cabs2(det);
    C2 idet; idet.x = det.x*id; idet.y = -det.y*id;
    C2 Vv[2][2];
    #pragma unroll
    for (int k = 0; k < 2; ++k)
      #pragma unroll
      for (int i = 0; i < 2; ++i){
        C2 t; t.x = E.p[k][i].x + 2.f*mu*E.g[k][i].x; t.y = E.p[k][i].y + 2.f*mu*E.g[k][i].y;
        Vv[i][k] = cmul(E.UW[k], cmul(t, idet));
      }
    if (!isP){
      Vs[n][0] = Vv[0][0].x; Vs[n][1] = Vv[0][0].y;
      Vs[n][2] = Vv[0][1].x; Vs[n][3] = Vv[0][1].y;
      Vs[n][4] = Vv[1][0].x; Vs[n][5] = Vv[1][0].y;
      Vs[n][6] = Vv[1][1].x; Vs[n][7] = Vv[1][1].y;
    } else {
      const float2 gg2 = g2[gid & 4095];
      C2 gc; gc.x = gg2.x; gc.y = gg2.y;
      float P = 0.f;
      #pragma unroll
      for (int k = 0; k < 2; ++k){
        const C2 a = Vv[0][k], b = Vv[1][k];
        P += cabs2(a) + cabs2(b);
        const C2 t = cmul(gc, cmul(a, conjc(b)));
        P += 2.f*t.x;
      }
      scs[n] = 1.41421356237f * rsqrtf(P);
    }
  }
  __syncthreads();

  const int t = tid & 63;
  const int ng = tid >> 6;
  const float4 f = *(const float4*)(frf + ((size_t)b2*64 + t)*2);
  C2 f0, f1; f0.x = f.x; f0.y = f.y; f1.x = f.z; f1.y = f.w;
  for (int n = ng; n < 32; n += 4){
    C2 M00, M01, M10, M11;
    M00.x = Vs[n][0]; M00.y = Vs[n][1]; M01.x = Vs[n][2]; M01.y = Vs[n][3];
    M10.x = Vs[n][4]; M10.y = Vs[n][5]; M11.x = Vs[n][6]; M11.y = Vs[n][7];
    const float sc = scs[n];
    const C2 c0 = cadd(cmul(f0, M00), cmul(f1, M10));
    const C2 c1 = cadd(cmul(f0, M01), cmul(f1, M11));
    const size_t base = (size_t)b2*8192 + n*128 + t*2;
    *(float2*)(out + base)        = make_float2(c0.x*sc, c1.x*sc);
    *(float2*)(out + base + 4096) = make_float2(c0.y*sc, c1.y*sc);
  }
}

// ---------------------------------------------------------------- launch
extern "C" void kernel_launch(void* const* d_in, const int* in_sizes, int n_in,
                              void* d_out, int out_size, void* d_ws, size_t ws_size,
                              hipStream_t stream)
{
  const float* H  = (const float*)d_in[0];
  const float* W0 = (const float*)d_in[1];
  const float* b0 = (const float*)d_in[2];
  const float* W1 = (const float*)d_in[3];
  const float* b1 = (const float*)d_in[4];
  const float* W2 = (const float*)d_in[5];
  const float* b2 = (const float*)d_in[6];
  const float* W3 = (const float*)d_in[7];
  const float* b3 = (const float*)d_in[8];
  float* out = (float*)d_out;
  char* ws = (char*)d_ws;
  (void)in_sizes; (void)n_in; (void)out_size; (void)ws_size;

  size_t o = 0;
  auto alloc = [&](size_t bytes) -> void* {
    void* p = ws + o;
    o += (bytes + 255) & ~(size_t)255;
    return p;
  };
  float2* frf   = (float2*)alloc((size_t)4096*64*2*sizeof(float2)); // 4 MiB
  float2* g2    = (float2*)alloc((size_t)4096*sizeof(float2));
  float*  xbuf  = (float*) alloc((size_t)M2N*8*sizeof(float));      // 4 MiB
  float*  ybuf  = (float*) alloc((size_t)M2N*8*sizeof(float));      // 4 MiB
  float*  coef  = (float*) alloc((size_t)M2N*8*sizeof(float));      // 4 MiB
  float*  slots = (float*) alloc(256*sizeof(float));                // 1 KiB
  f16*    wfr12 = (f16*)   alloc((size_t)256*1024*sizeof(f16));     // 512 KiB
  f16*    wfr0  = (f16*)   alloc((size_t)16*1024*sizeof(f16));      // 32 KiB
  f16*    wfr3  = (f16*)   alloc((size_t)8*1024*sizeof(f16));       // 16 KiB

  k_prep<<<66, 256, 0, stream>>>(W0, W1, W2, W3, wfr12, wfr0, wfr3, slots);
  k_frf<<<2048, 256, 0, stream>>>(H, frf, g2);
  k_hequ<<<32768, 256, 0, stream>>>(H, frf, xbuf);
  k_mlp<<<2731, 256, 0, stream>>>(xbuf, wfr12, wfr0, wfr3, b0, b1, b2, b3, ybuf);
  k_coef<<<512, 256, 0, stream>>>(xbuf, ybuf, coef);
  k_red<0,5><<<512, 256, 0, stream>>>(coef, slots);
  k_red<1,5><<<512, 256, 0, stream>>>(coef, slots);
  k_red<2,5><<<512, 256, 0, stream>>>(coef, slots);
  k_red<3,4><<<512, 256, 0, stream>>>(coef, slots);
  k_out<<<4096, 256, 0, stream>>>(frf, xbuf, ybuf, g2, slots, out);
}

// Round 12
// 268.210 us; speedup vs baseline: 1.0682x; 1.0339x over previous
//
#include <hip/hip_runtime.h>

typedef _Float16 f16;
typedef __attribute__((ext_vector_type(8))) _Float16 f16x8;
typedef __attribute__((ext_vector_type(4))) _Float16 f16x4;
typedef __attribute__((ext_vector_type(4))) float f32x4;
typedef unsigned int u32;

#define M2N 131072   // BATCH(4096) * Nc(32)
#define MFMA16 __builtin_amdgcn_mfma_f32_16x16x32_f16

struct C2 { float x, y; };
__device__ __forceinline__ C2 cmul(C2 a, C2 b){ C2 r; r.x = a.x*b.x - a.y*b.y; r.y = a.x*b.y + a.y*b.x; return r; }
__device__ __forceinline__ C2 cadd(C2 a, C2 b){ C2 r; r.x = a.x+b.x; r.y = a.y+b.y; return r; }
__device__ __forceinline__ C2 csub(C2 a, C2 b){ C2 r; r.x = a.x-b.x; r.y = a.y-b.y; return r; }
__device__ __forceinline__ C2 conjc(C2 a){ C2 r; r.x = a.x; r.y = -a.y; return r; }
__device__ __forceinline__ C2 cneg(C2 a){ C2 r; r.x = -a.x; r.y = -a.y; return r; }
__device__ __forceinline__ float cabs2(C2 a){ return a.x*a.x + a.y*a.y; }
__device__ __forceinline__ float dotr(C2 a, C2 b){ return a.x*b.x + a.y*b.y; }

__device__ __forceinline__ float wred(float v){
  #pragma unroll
  for (int s = 32; s > 0; s >>= 1) v += __shfl_xor(v, s, 64);
  return v;
}

// Inline F_RF for (b2, t=lane): bit-exact with the former k_frf.
// f = (F0.x, F0.y, F1.x, F1.y) for subcarrier c=16.
__device__ __forceinline__ float4 frf_inline(const float* __restrict__ H, int b2, int lane){
  const size_t cb0 = ((size_t)(b2*2 + 0)*32 + 16)*128;
  const size_t cb1 = ((size_t)(b2*2 + 1)*32 + 16)*128;
  const float ar0 = H[cb0 + lane], ai0 = H[cb0];
  const float ar1 = H[cb1 + lane], ai1 = H[cb1];
  const float i0 = rsqrtf(ar0*ar0 + ai0*ai0) * 0.125f;
  const float i1 = rsqrtf(ar1*ar1 + ai1*ai1) * 0.125f;
  float4 f;
  f.x = ar0*i0; f.y = -ai0*i0;
  f.z = ar1*i1; f.w = -ai1*i1;
  return f;
}

// ---------------------------------------------------------------- prep
// Frag-linear hi/lo f16 weight fragments for 16x16x32 MFMA.
// Frag layout (both operands identical): lane l holds [idx0=l&15][k=(l>>4)*8+e].
__global__ void k_prep(const float* __restrict__ W0, const float* __restrict__ W1,
                       const float* __restrict__ W2, const float* __restrict__ W3,
                       f16* __restrict__ wfr12, f16* __restrict__ wfr0,
                       f16* __restrict__ wfr3, float* __restrict__ slots)
{
  const int b = blockIdx.x, tid = threadIdx.x;
  if (b < 64){
    const int slot = b*256 + tid;        // [0, 16384)
    const int lane = slot & 63;
    const int rest = slot >> 6;          // L*128 + nt*8 + kt
    const int kt = rest & 7, nt = (rest >> 3) & 15, L = rest >> 7;
    const float* W = L ? W2 : W1;
    const int n = nt*16 + (lane & 15);
    f16* dst = wfr12 + (size_t)rest*1024 + lane*8;
    #pragma unroll
    for (int e = 0; e < 8; ++e){
      const int k = kt*32 + (lane>>4)*8 + e;
      const float w = W[k*256 + n];
      const f16 h = (f16)w;
      dst[e] = h; dst[512+e] = (f16)(w - (float)h);
    }
  } else if (b == 64){
    for (int i = 0; i < 4; ++i){
      const int slot = i*256 + tid;      // [0,1024)
      const int lane = slot & 63, nt = slot >> 6;
      const int col = nt*16 + (lane & 15);
      f16* dst = wfr0 + (size_t)nt*1024 + lane*8;
      #pragma unroll
      for (int e = 0; e < 8; ++e){
        const int k = (lane>>4)*8 + e;
        const float w = (k < 8) ? W0[k*256 + col] : 0.f;
        const f16 h = (f16)w;
        dst[e] = h; dst[512+e] = (f16)(w - (float)h);
      }
    }
  } else {
    slots[tid] = 0.f;   // zero bisection accumulators (256 floats)
    for (int i = 0; i < 2; ++i){
      const int slot = i*256 + tid;      // [0,512)
      const int lane = slot & 63, kt = slot >> 6;
      const int col = lane & 15;
      f16* dst = wfr3 + (size_t)kt*1024 + lane*8;
      #pragma unroll
      for (int e = 0; e < 8; ++e){
        const int k = kt*32 + (lane>>4)*8 + e;
        const float w = (col < 8) ? W3[k*8 + col] : 0.f;
        const f16 h = (f16)w;
        dst[e] = h; dst[512+e] = (f16)(w - (float)h);
      }
    }
  }
}

// ---------------------------------------------------------------- H_equ -> x  (+g2)
__global__ void k_hequ(const float* __restrict__ H, float* __restrict__ x,
                       float2* __restrict__ g2)
{
  const int m2 = blockIdx.x*4 + (threadIdx.x >> 6);
  const int lane = threadIdx.x & 63;
  const int n = m2 >> 12, b2 = m2 & 4095;
  const float4 f = frf_inline(H, b2, lane);
  if (n == 0){   // this wave owns b2: emit g2[b2] (bit-exact former k_frf reduce)
    float re = f.x*f.z + f.y*f.w;          // F0 * conj(F1)
    float im = f.y*f.z - f.x*f.w;
    re = wred(re); im = wred(im);
    if (lane == 0){ float2 g; g.x = re; g.y = im; g2[b2] = g; }
  }
  float accr[2][2], acci[2][2];
  #pragma unroll
  for (int i = 0; i < 2; ++i){
    const float* hr = H + (size_t)(n*8192 + b2*2 + i) * 128;
    const float re = hr[lane];
    const float im = hr[0];
    accr[i][0] = re*f.x - im*f.y;  acci[i][0] = re*f.y + im*f.x;
    accr[i][1] = re*f.z - im*f.w;  acci[i][1] = re*f.w + im*f.z;
  }
  #pragma unroll
  for (int i = 0; i < 2; ++i)
    #pragma unroll
    for (int j = 0; j < 2; ++j){ accr[i][j] = wred(accr[i][j]); acci[i][j] = wred(acci[i][j]); }
  if (lane == 0){
    float pw = 0.f;
    #pragma unroll
    for (int i = 0; i < 2; ++i)
      #pragma unroll
      for (int j = 0; j < 2; ++j) pw += accr[i][j]*accr[i][j] + acci[i][j]*acci[i][j];
    const float rs = rsqrtf(pw);
    *(float4*)(x + (size_t)m2*8)     = make_float4(accr[0][0]*rs, accr[0][1]*rs, accr[1][0]*rs, accr[1][1]*rs);
    *(float4*)(x + (size_t)m2*8 + 4) = make_float4(acci[0][0]*rs, acci[0][1]*rs, acci[1][0]*rs, acci[1][1]*rs);
  }
}

// ---------------------------------------------------------------- fused MLP
// 48-row tiles (LDS 48KB -> 3 blocks/CU). Operand-swapped MFMA (acc = D[n][m]),
// two-plane f16 activations, 8-granule XOR swizzle.
// NOTE (r10 post-mortem): manual B-register pipelining / fused tails cause
// scratch spills. Keep register-lean (72 VGPR): best measured 106 us, MfmaUtil 53%.
#define SWX(r, c) ((r)*256 + ((c) ^ (((r)&7)<<3)))

__launch_bounds__(256, 3)
__global__ void k_mlp(const float* __restrict__ x, const f16* __restrict__ wfr12,
                      const f16* __restrict__ wfr0, const f16* __restrict__ wfr3,
                      const float* __restrict__ bias0, const float* __restrict__ bias1,
                      const float* __restrict__ bias2, const float* __restrict__ bias3,
                      float* __restrict__ y)
{
  __shared__ __align__(16) f16 xah[48*256];   // 24 KiB
  __shared__ __align__(16) f16 xal[48*256];   // 24 KiB
  const int tid = threadIdx.x, blk = blockIdx.x;
  const int lane = tid & 63, wv = tid >> 6;
  const int l15 = lane & 15, lh = lane >> 4;
  const int colb = wv*64;

  f32x4 acc[3][4];
  f16x8 ah[3], al[3], bh[4], bl[4];

  auto EPI = [&](){   // relu + exact f16 split + two-plane b64 swizzled writes
    #pragma unroll
    for (int Mt = 0; Mt < 3; ++Mt)
      #pragma unroll
      for (int nt = 0; nt < 4; ++nt){
        f16x4 h4, l4;
        #pragma unroll
        for (int r = 0; r < 4; ++r){
          const float v = fmaxf(acc[Mt][nt][r], 0.f);
          const f16 h = (f16)v;
          h4[r] = h; l4[r] = (f16)(v - (float)h);
        }
        const int idx = SWX(Mt*16 + l15, colb + nt*16 + lh*4);
        *(f16x4*)(xah + idx) = h4;
        *(f16x4*)(xal + idx) = l4;
      }
  };

  // ---------- layer 0 (8 -> 256, K padded to 32; zero-padded W kills garbage k)
  #pragma unroll
  for (int nt = 0; nt < 4; ++nt){
    const f32x4 b4 = *(const f32x4*)(bias0 + colb + nt*16 + lh*4);
    #pragma unroll
    for (int Mt = 0; Mt < 3; ++Mt) acc[Mt][nt] = b4;
  }
  #pragma unroll
  for (int Mt = 0; Mt < 3; ++Mt){
    const int row = blk*48 + Mt*16 + l15;   // tail rows read stale ws (finite), discarded
    const float* xr = x + (size_t)row*8;
    const float4 v0 = *(const float4*)xr;
    const float4 v1 = *(const float4*)(xr+4);
    const float vv[8] = {v0.x,v0.y,v0.z,v0.w,v1.x,v1.y,v1.z,v1.w};
    #pragma unroll
    for (int e = 0; e < 8; ++e){
      const f16 h = (f16)vv[e];
      ah[Mt][e] = h; al[Mt][e] = (f16)(vv[e] - (float)h);
    }
  }
  #pragma unroll
  for (int nt = 0; nt < 4; ++nt){
    bh[nt] = *(const f16x8*)(wfr0 + (size_t)(wv*4+nt)*1024 + lane*8);
    bl[nt] = *(const f16x8*)(wfr0 + (size_t)(wv*4+nt)*1024 + 512 + lane*8);
  }
  #pragma unroll
  for (int Mt = 0; Mt < 3; ++Mt)
    #pragma unroll
    for (int nt = 0; nt < 4; ++nt){
      acc[Mt][nt] = MFMA16(bh[nt], ah[Mt], acc[Mt][nt], 0, 0, 0);
      acc[Mt][nt] = MFMA16(bh[nt], al[Mt], acc[Mt][nt], 0, 0, 0);
      acc[Mt][nt] = MFMA16(bl[nt], ah[Mt], acc[Mt][nt], 0, 0, 0);
    }
  EPI();
  __syncthreads();

  // ---------- layers 1,2 (256 -> 256)
  for (int L = 0; L < 2; ++L){
    const float* bs = L ? bias2 : bias1;
    #pragma unroll
    for (int nt = 0; nt < 4; ++nt){
      const f32x4 b4 = *(const f32x4*)(bs + colb + nt*16 + lh*4);
      #pragma unroll
      for (int Mt = 0; Mt < 3; ++Mt) acc[Mt][nt] = b4;
    }
    #pragma unroll 2
    for (int kt = 0; kt < 8; ++kt){
      #pragma unroll
      for (int Mt = 0; Mt < 3; ++Mt){
        const int idx = SWX(Mt*16 + l15, kt*32 + lh*8);
        ah[Mt] = *(const f16x8*)(xah + idx);
        al[Mt] = *(const f16x8*)(xal + idx);
      }
      #pragma unroll
      for (int nt = 0; nt < 4; ++nt){
        const size_t f = ((size_t)(L*128 + (wv*4+nt)*8 + kt))*1024;
        bh[nt] = *(const f16x8*)(wfr12 + f + lane*8);
        bl[nt] = *(const f16x8*)(wfr12 + f + 512 + lane*8);
      }
      #pragma unroll
      for (int Mt = 0; Mt < 3; ++Mt)
        #pragma unroll
        for (int nt = 0; nt < 4; ++nt){
          acc[Mt][nt] = MFMA16(bh[nt], ah[Mt], acc[Mt][nt], 0, 0, 0);
          acc[Mt][nt] = MFMA16(bh[nt], al[Mt], acc[Mt][nt], 0, 0, 0);
          acc[Mt][nt] = MFMA16(bl[nt], ah[Mt], acc[Mt][nt], 0, 0, 0);
        }
    }
    __syncthreads();   // all reads done before overwrite
    EPI();
    __syncthreads();
  }

  // ---------- layer 3 (256 -> 8, N padded to 16; zero-padded W cols)
  f32x4 a3[3];
  {
    f32x4 b4 = {0.f, 0.f, 0.f, 0.f};
    if (lh < 2) b4 = *(const f32x4*)(bias3 + lh*4);
    #pragma unroll
    for (int Mt = 0; Mt < 3; ++Mt) a3[Mt] = b4;
  }
  #pragma unroll 2
  for (int kt = 0; kt < 8; ++kt){
    #pragma unroll
    for (int Mt = 0; Mt < 3; ++Mt){
      const int idx = SWX(Mt*16 + l15, kt*32 + lh*8);
      ah[Mt] = *(const f16x8*)(xah + idx);
      al[Mt] = *(const f16x8*)(xal + idx);
    }
    const f16x8 b3h = *(const f16x8*)(wfr3 + (size_t)kt*1024 + lane*8);
    const f16x8 b3l = *(const f16x8*)(wfr3 + (size_t)kt*1024 + 512 + lane*8);
    #pragma unroll
    for (int Mt = 0; Mt < 3; ++Mt){
      a3[Mt] = MFMA16(b3h, ah[Mt], a3[Mt], 0, 0, 0);
      a3[Mt] = MFMA16(b3h, al[Mt], a3[Mt], 0, 0, 0);
      a3[Mt] = MFMA16(b3l, ah[Mt], a3[Mt], 0, 0, 0);
    }
  }
  if (lh < 2){
    #pragma unroll
    for (int Mt = 0; Mt < 3; ++Mt){
      const int row = blk*48 + Mt*16 + l15;
      if (row < M2N) *(f32x4*)(y + (size_t)row*8 + lh*4) = a3[Mt];
    }
  }
}

// ---------------------------------------------------------------- per-element algebra
struct Elem {
  C2 p[2][2], g[2][2], UW[2], d0, d1;
  float A0, A1, A2, c0, c1, c2, c3;
};
struct Coef { float A0, A1, A2, c0, c1, c2, c3; };

__device__ __forceinline__ void elem_core(const float* __restrict__ x,
                                          const float* __restrict__ y,
                                          int gid, Elem& E)
{
  const float4 xr = *(const float4*)(x + (size_t)gid*8);
  const float4 xi = *(const float4*)(x + (size_t)gid*8 + 4);
  C2 h[2][2];
  h[0][0].x = xr.x; h[0][0].y = xi.x; h[0][1].x = xr.y; h[0][1].y = xi.y;
  h[1][0].x = xr.z; h[1][0].y = xi.z; h[1][1].x = xr.w; h[1][1].y = xi.w;
  const float4 ya = *(const float4*)(y + (size_t)gid*8);
  const float4 yb = *(const float4*)(y + (size_t)gid*8 + 4);
  C2 U[2], Wm[2];
  U[0].x = ya.x; U[0].y = ya.z;  U[1].x = ya.y; U[1].y = ya.w;
  Wm[0].x = yb.x; Wm[0].y = yb.z; Wm[1].x = yb.y; Wm[1].y = yb.w;
  const float u20 = cabs2(U[0]), u21 = cabs2(U[1]);
  C2 cf[2];
  cf[0].x = Wm[0].x*u20; cf[0].y = Wm[0].y*u20;
  cf[1].x = Wm[1].x*u21; cf[1].y = Wm[1].y*u21;
  C2 B[2][2];
  #pragma unroll
  for (int i = 0; i < 2; ++i)
    #pragma unroll
    for (int j = 0; j < 2; ++j){
      const C2 t0 = cmul(conjc(h[0][i]), h[0][j]);
      const C2 t1 = cmul(conjc(h[1][i]), h[1][j]);
      B[i][j] = cadd(cmul(cf[0], t0), cmul(cf[1], t1));
    }
  C2 adj[2][2];
  adj[0][0] = B[1][1]; adj[0][1] = cneg(B[0][1]);
  adj[1][0] = cneg(B[1][0]); adj[1][1] = B[0][0];
  E.d0 = csub(cmul(B[0][0], B[1][1]), cmul(B[0][1], B[1][0]));
  E.d1.x = 2.f*(B[0][0].x + B[1][1].x);
  E.d1.y = 2.f*(B[0][0].y + B[1][1].y);
  #pragma unroll
  for (int k = 0; k < 2; ++k){
    #pragma unroll
    for (int j = 0; j < 2; ++j) E.g[k][j] = conjc(h[k][j]);
    #pragma unroll
    for (int i = 0; i < 2; ++i)
      E.p[k][i] = cadd(cmul(adj[i][0], E.g[k][0]), cmul(adj[i][1], E.g[k][1]));
    E.UW[k] = cmul(U[k], Wm[k]);
  }
  const float w0 = cabs2(E.UW[0]), w1 = cabs2(E.UW[1]);
  E.A0 = w0*(cabs2(E.p[0][0]) + cabs2(E.p[0][1])) + w1*(cabs2(E.p[1][0]) + cabs2(E.p[1][1]));
  E.A1 = 4.f*( w0*(dotr(E.p[0][0], E.g[0][0]) + dotr(E.p[0][1], E.g[0][1]))
             + w1*(dotr(E.p[1][0], E.g[1][0]) + dotr(E.p[1][1], E.g[1][1])) );
  E.A2 = 4.f*( w0*(cabs2(E.g[0][0]) + cabs2(E.g[0][1]))
             + w1*(cabs2(E.g[1][0]) + cabs2(E.g[1][1])) );
  E.c0 = cabs2(E.d0);
  E.c1 = 2.f*(E.d0.x*E.d1.x + E.d0.y*E.d1.y);
  E.c2 = cabs2(E.d1) + 8.f*E.d0.x;
  E.c3 = 8.f*E.d1.x;
}

// ---------------------------------------------------------------- bisection machinery
__device__ __forceinline__ float evalf(float mu, const Coef& C){
  const float num = C.A0 + mu*(C.A1 + mu*C.A2);
  const float den = C.c0 + mu*(C.c1 + mu*(C.c2 + mu*(C.c3 + mu*16.f)));
  return num/den;
}

// Replay nrounds of multi-level bisection decisions from slot sums.
// Candidates mu(d,k) = lo0 + span*(2k+1)/2^(d+1), closed form; identical
// expressions in eval and replay -> internally consistent.
__device__ __forceinline__ void replay(const float* __restrict__ slots, int nrounds,
                                       float& lo, float& hi)
{
  const int DP[4] = {5, 5, 5, 4};
  for (int r = 0; r < nrounds; ++r){
    const float lo0 = lo, span = hi - lo;
    int k = 0;
    for (int d = 0; d < DP[r]; ++d){
      const float sd = span * (1.0f / (float)(1 << (d+1)));
      const float mu = fmaf((float)(2*k + 1), sd, lo0);
      const bool big = slots[r*32 + (1 << d) - 1 + k] > 1.0f;
      lo = big ? mu : lo;
      hi = big ? hi : mu;
      k = 2*k + (big ? 1 : 0);
    }
  }
}

// Depth-D candidate-subtree evaluation + block reduce + atomicAdd into slots.
template<int D>
__device__ __forceinline__ void eval_round(const Coef& C, float lo, float hi,
                                           float* __restrict__ slots, int roundBase,
                                           float (*r4)[32])
{
  const int tid = threadIdx.x;
  const int lane = tid & 63, wv = tid >> 6;
  const float lo0 = lo, span = hi - lo;
  int node = 0;
  #pragma unroll
  for (int d = 0; d < D; ++d){
    const float sd = span * (1.0f / (float)(1 << (d+1)));
    for (int k = 0; k < (1 << d); ++k){
      const float mu = fmaf((float)(2*k + 1), sd, lo0);
      const float f = wred(evalf(mu, C));
      if (lane == 0) r4[wv][node] = f;
      ++node;
    }
  }
  __syncthreads();
  if (tid < (1 << D) - 1)
    atomicAdd(&slots[roundBase + tid], r4[0][tid] + r4[1][tid] + r4[2][tid] + r4[3][tid]);
}

// Round 0: fused coef computation (elem_core from x,y) + depth-5 eval.
__launch_bounds__(256)
__global__ void k_red0(const float* __restrict__ x, const float* __restrict__ y,
                       float* __restrict__ coef, float* __restrict__ slots)
{
  const int gid = blockIdx.x*256 + threadIdx.x;
  __shared__ float r4[4][32];
  Elem E;
  elem_core(x, y, gid, E);
  *(float4*)(coef + (size_t)gid*8)     = make_float4(E.A0, E.A1, E.A2, E.c0);
  *(float4*)(coef + (size_t)gid*8 + 4) = make_float4(E.c1, E.c2, E.c3, 0.f);
  Coef C; C.A0 = E.A0; C.A1 = E.A1; C.A2 = E.A2; C.c0 = E.c0;
  C.c1 = E.c1; C.c2 = E.c2; C.c3 = E.c3;
  eval_round<5>(C, 0.f, 10.f, slots, 0, r4);
}

// Rounds 1..3: LDS-cached slot replay + depth-D eval.
template<int ROUND, int D>
__launch_bounds__(256)
__global__ void k_red(const float* __restrict__ coef, float* __restrict__ slots)
{
  const int tid = threadIdx.x;
  const int gid = blockIdx.x*256 + tid;
  __shared__ float r4[4][32];
  __shared__ float sl[96];
  if (tid < ROUND*32) sl[tid] = slots[tid];

  const float4 a = *(const float4*)(coef + (size_t)gid*8);
  const float4 b = *(const float4*)(coef + (size_t)gid*8 + 4);
  Coef C; C.A0 = a.x; C.A1 = a.y; C.A2 = a.z; C.c0 = a.w;
  C.c1 = b.x; C.c2 = b.y; C.c3 = b.z;
  __syncthreads();

  float lo = 0.f, hi = 10.f;
  replay(sl, ROUND, lo, hi);
  eval_round<D>(C, lo, hi, slots, ROUND*32, r4);
}

// ---------------------------------------------------------------- output (+final V,Pm)
// Per b2-block: wave 0 builds F_RF inline into LDS; threads 0..31 compute V at
// gid=n*4096+b2; threads 32..63 compute the (quirky) power normalizer at
// gid=b2*32+n (g2 index (gid&4095) from global). Then 256 threads do F_RF @ V.
__global__ void k_out(const float* __restrict__ H, const float* __restrict__ x,
                      const float* __restrict__ y, const float2* __restrict__ g2,
                      const float* __restrict__ slots, float* __restrict__ out)
{
  const int b2 = blockIdx.x;
  const int tid = threadIdx.x;
  __shared__ float4 fs[64];
  __shared__ float Vs[32][8];
  __shared__ float scs[32];
  __shared__ float sl[128];

  if (tid >= 128) sl[tid - 128] = slots[tid - 128];
  if (tid < 64) fs[tid] = frf_inline(H, b2, tid);
  __syncthreads();

  if (tid < 64){
    const int n = tid & 31;
    const bool isP = tid >= 32;
    const int gid = isP ? (b2*32 + n) : (n*4096 + b2);
    float lo = 0.f, hi = 10.f;
    replay(sl, 4, lo, hi);
    const float mu = 0.5f*(lo + hi);   // 20th midpoint
    Elem E;
    elem_core(x, y, gid, E);
    C2 det; det.x = E.d0.x + mu*E.d1.x + 4.f*mu*mu; det.y = E.d0.y + mu*E.d1.y;
    const float id = 1.f/cabs2(det);
    C2 idet; idet.x = det.x*id; idet.y = -det.y*id;
    C2 Vv[2][2];
    #pragma unroll
    for (int k = 0; k < 2; ++k)
      #pragma unroll
      for (int i = 0; i < 2; ++i){
        C2 t; t.x = E.p[k][i].x + 2.f*mu*E.g[k][i].x; t.y = E.p[k][i].y + 2.f*mu*E.g[k][i].y;
        Vv[i][k] = cmul(E.UW[k], cmul(t, idet));
      }
    if (!isP){
      Vs[n][0] = Vv[0][0].x; Vs[n][1] = Vv[0][0].y;
      Vs[n][2] = Vv[0][1].x; Vs[n][3] = Vv[0][1].y;
      Vs[n][4] = Vv[1][0].x; Vs[n][5] = Vv[1][0].y;
      Vs[n][6] = Vv[1][1].x; Vs[n][7] = Vv[1][1].y;
    } else {
      const float2 gg2 = g2[gid & 4095];
      C2 gc; gc.x = gg2.x; gc.y = gg2.y;
      float P = 0.f;
      #pragma unroll
      for (int k = 0; k < 2; ++k){
        const C2 a = Vv[0][k], b = Vv[1][k];
        P += cabs2(a) + cabs2(b);
        const C2 t = cmul(gc, cmul(a, conjc(b)));
        P += 2.f*t.x;
      }
      scs[n] = 1.41421356237f * rsqrtf(P);
    }
  }
  __syncthreads();

  const int t = tid & 63;
  const int ng = tid >> 6;
  const float4 f = fs[t];
  C2 f0, f1; f0.x = f.x; f0.y = f.y; f1.x = f.z; f1.y = f.w;
  for (int n = ng; n < 32; n += 4){
    C2 M00, M01, M10, M11;
    M00.x = Vs[n][0]; M00.y = Vs[n][1]; M01.x = Vs[n][2]; M01.y = Vs[n][3];
    M10.x = Vs[n][4]; M10.y = Vs[n][5]; M11.x = Vs[n][6]; M11.y = Vs[n][7];
    const float sc = scs[n];
    const C2 c0 = cadd(cmul(f0, M00), cmul(f1, M10));
    const C2 c1 = cadd(cmul(f0, M01), cmul(f1, M11));
    const size_t base = (size_t)b2*8192 + n*128 + t*2;
    *(float2*)(out + base)        = make_float2(c0.x*sc, c1.x*sc);
    *(float2*)(out + base + 4096) = make_float2(c0.y*sc, c1.y*sc);
  }
}

// ---------------------------------------------------------------- launch
extern "C" void kernel_launch(void* const* d_in, const int* in_sizes, int n_in,
                              void* d_out, int out_size, void* d_ws, size_t ws_size,
                              hipStream_t stream)
{
  const float* H  = (const float*)d_in[0];
  const float* W0 = (const float*)d_in[1];
  const float* b0 = (const float*)d_in[2];
  const float* W1 = (const float*)d_in[3];
  const float* b1 = (const float*)d_in[4];
  const float* W2 = (const float*)d_in[5];
  const float* b2 = (const float*)d_in[6];
  const float* W3 = (const float*)d_in[7];
  const float* b3 = (const float*)d_in[8];
  float* out = (float*)d_out;
  char* ws = (char*)d_ws;
  (void)in_sizes; (void)n_in; (void)out_size; (void)ws_size;

  size_t o = 0;
  auto alloc = [&](size_t bytes) -> void* {
    void* p = ws + o;
    o += (bytes + 255) & ~(size_t)255;
    return p;
  };
  float2* g2    = (float2*)alloc((size_t)4096*sizeof(float2));      // 32 KiB
  float*  xbuf  = (float*) alloc((size_t)M2N*8*sizeof(float));      // 4 MiB
  float*  ybuf  = (float*) alloc((size_t)M2N*8*sizeof(float));      // 4 MiB
  float*  coef  = (float*) alloc((size_t)M2N*8*sizeof(float));      // 4 MiB
  float*  slots = (float*) alloc(256*sizeof(float));                // 1 KiB
  f16*    wfr12 = (f16*)   alloc((size_t)256*1024*sizeof(f16));     // 512 KiB
  f16*    wfr0  = (f16*)   alloc((size_t)16*1024*sizeof(f16));      // 32 KiB
  f16*    wfr3  = (f16*)   alloc((size_t)8*1024*sizeof(f16));       // 16 KiB

  k_prep<<<66, 256, 0, stream>>>(W0, W1, W2, W3, wfr12, wfr0, wfr3, slots);
  k_hequ<<<32768, 256, 0, stream>>>(H, xbuf, g2);
  k_mlp<<<2731, 256, 0, stream>>>(xbuf, wfr12, wfr0, wfr3, b0, b1, b2, b3, ybuf);
  k_red0<<<512, 256, 0, stream>>>(xbuf, ybuf, coef, slots);
  k_red<1,5><<<512, 256, 0, stream>>>(coef, slots);
  k_red<2,5><<<512, 256, 0, stream>>>(coef, slots);
  k_red<3,4><<<512, 256, 0, stream>>>(coef, slots);
  k_out<<<4096, 256, 0, stream>>>(H, xbuf, ybuf, g2, slots, out);
}

// Round 13
// 242.610 us; speedup vs baseline: 1.1809x; 1.1055x over previous
//
#include <hip/hip_runtime.h>

typedef _Float16 f16;
typedef __attribute__((ext_vector_type(8))) _Float16 f16x8;
typedef __attribute__((ext_vector_type(4))) _Float16 f16x4;
typedef __attribute__((ext_vector_type(4))) float f32x4;
typedef unsigned int u32;

#define M2N 131072   // BATCH(4096) * Nc(32)
#define MFMA16 __builtin_amdgcn_mfma_f32_16x16x32_f16

struct C2 { float x, y; };
__device__ __forceinline__ C2 cmul(C2 a, C2 b){ C2 r; r.x = a.x*b.x - a.y*b.y; r.y = a.x*b.y + a.y*b.x; return r; }
__device__ __forceinline__ C2 cadd(C2 a, C2 b){ C2 r; r.x = a.x+b.x; r.y = a.y+b.y; return r; }
__device__ __forceinline__ C2 csub(C2 a, C2 b){ C2 r; r.x = a.x-b.x; r.y = a.y-b.y; return r; }
__device__ __forceinline__ C2 conjc(C2 a){ C2 r; r.x = a.x; r.y = -a.y; return r; }
__device__ __forceinline__ C2 cneg(C2 a){ C2 r; r.x = -a.x; r.y = -a.y; return r; }
__device__ __forceinline__ float cabs2(C2 a){ return a.x*a.x + a.y*a.y; }
__device__ __forceinline__ float dotr(C2 a, C2 b){ return a.x*b.x + a.y*b.y; }

__device__ __forceinline__ float wred(float v){
  #pragma unroll
  for (int s = 32; s > 0; s >>= 1) v += __shfl_xor(v, s, 64);
  return v;
}

// Inline F_RF for (b2, t=lane): bit-exact with the former k_frf.
__device__ __forceinline__ float4 frf_inline(const float* __restrict__ H, int b2, int lane){
  const size_t cb0 = ((size_t)(b2*2 + 0)*32 + 16)*128;
  const size_t cb1 = ((size_t)(b2*2 + 1)*32 + 16)*128;
  const float ar0 = H[cb0 + lane], ai0 = H[cb0];
  const float ar1 = H[cb1 + lane], ai1 = H[cb1];
  const float i0 = rsqrtf(ar0*ar0 + ai0*ai0) * 0.125f;
  const float i1 = rsqrtf(ar1*ar1 + ai1*ai1) * 0.125f;
  float4 f;
  f.x = ar0*i0; f.y = -ai0*i0;
  f.z = ar1*i1; f.w = -ai1*i1;
  return f;
}

// ---------------------------------------------------------------- prep
__global__ void k_prep(const float* __restrict__ W0, const float* __restrict__ W1,
                       const float* __restrict__ W2, const float* __restrict__ W3,
                       f16* __restrict__ wfr12, f16* __restrict__ wfr0,
                       f16* __restrict__ wfr3, float* __restrict__ slots)
{
  const int b = blockIdx.x, tid = threadIdx.x;
  if (b < 64){
    const int slot = b*256 + tid;        // [0, 16384)
    const int lane = slot & 63;
    const int rest = slot >> 6;          // L*128 + nt*8 + kt
    const int kt = rest & 7, nt = (rest >> 3) & 15, L = rest >> 7;
    const float* W = L ? W2 : W1;
    const int n = nt*16 + (lane & 15);
    f16* dst = wfr12 + (size_t)rest*1024 + lane*8;
    #pragma unroll
    for (int e = 0; e < 8; ++e){
      const int k = kt*32 + (lane>>4)*8 + e;
      const float w = W[k*256 + n];
      const f16 h = (f16)w;
      dst[e] = h; dst[512+e] = (f16)(w - (float)h);
    }
  } else if (b == 64){
    for (int i = 0; i < 4; ++i){
      const int slot = i*256 + tid;      // [0,1024)
      const int lane = slot & 63, nt = slot >> 6;
      const int col = nt*16 + (lane & 15);
      f16* dst = wfr0 + (size_t)nt*1024 + lane*8;
      #pragma unroll
      for (int e = 0; e < 8; ++e){
        const int k = (lane>>4)*8 + e;
        const float w = (k < 8) ? W0[k*256 + col] : 0.f;
        const f16 h = (f16)w;
        dst[e] = h; dst[512+e] = (f16)(w - (float)h);
      }
    }
  } else {
    slots[tid] = 0.f;   // zero bisection accumulators (256 floats)
    for (int i = 0; i < 2; ++i){
      const int slot = i*256 + tid;      // [0,512)
      const int lane = slot & 63, kt = slot >> 6;
      const int col = lane & 15;
      f16* dst = wfr3 + (size_t)kt*1024 + lane*8;
      #pragma unroll
      for (int e = 0; e < 8; ++e){
        const int k = kt*32 + (lane>>4)*8 + e;
        const float w = (col < 8) ? W3[k*8 + col] : 0.f;
        const f16 h = (f16)w;
        dst[e] = h; dst[512+e] = (f16)(w - (float)h);
      }
    }
  }
}

// ---------------------------------------------------------------- H_equ -> x  (+g2)
// LDS-transpose reduction (22 DS ops/wave vs 96 with butterfly-wred):
// store word(q,l) = q*64 + (l&56) + (((l&7)+q)&7)  -- +q rotation spreads every
// store/load instruction across 32 banks (2 lanes/bank = free).
__global__ void k_hequ(const float* __restrict__ H, float* __restrict__ x,
                       float2* __restrict__ g2)
{
  __shared__ float vbuf[4][512];   // 8 KiB, wave-private regions
  const int wv = threadIdx.x >> 6;
  const int m2 = blockIdx.x*4 + wv;
  const int lane = threadIdx.x & 63;
  const int n = m2 >> 12, b2 = m2 & 4095;
  const float4 f = frf_inline(H, b2, lane);
  if (n == 0){   // this wave owns b2: emit g2[b2] (bit-exact former k_frf reduce)
    float re = f.x*f.z + f.y*f.w;          // F0 * conj(F1)
    float im = f.y*f.z - f.x*f.w;
    re = wred(re); im = wred(im);
    if (lane == 0){ float2 g; g.x = re; g.y = im; g2[b2] = g; }
  }
  const float* h0 = H + (size_t)(n*8192 + b2*2 + 0) * 128;
  const float* h1 = H + (size_t)(n*8192 + b2*2 + 1) * 128;
  const float re0 = h0[lane], im0 = h0[0];
  const float re1 = h1[lane], im1 = h1[0];
  float v[8];
  v[0] = re0*f.x - im0*f.y;   // accr[0][0]
  v[1] = re0*f.z - im0*f.w;   // accr[0][1]
  v[2] = re1*f.x - im1*f.y;   // accr[1][0]
  v[3] = re1*f.z - im1*f.w;   // accr[1][1]
  v[4] = re0*f.y + im0*f.x;   // acci[0][0]
  v[5] = re0*f.w + im0*f.z;   // acci[0][1]
  v[6] = re1*f.y + im1*f.x;   // acci[1][0]
  v[7] = re1*f.w + im1*f.z;   // acci[1][1]
  float* wb = vbuf[wv];
  #pragma unroll
  for (int q = 0; q < 8; ++q)
    wb[q*64 + (lane & 56) + (((lane & 7) + q) & 7)] = v[q];
  // stage 1: lane l sums quantity q=l>>3 over source group g=l&7 (8 lanes)
  const int q = lane >> 3, g = lane & 7;
  float s = 0.f;
  #pragma unroll
  for (int j = 0; j < 8; ++j)
    s += wb[q*64 + g*8 + ((j + q) & 7)];
  // stage 2a: sum partials over g within the 8-lane group (xor 1,2,4)
  #pragma unroll
  for (int d = 1; d < 8; d <<= 1) s += __shfl_xor(s, d, 64);
  // stage 2b: pw = sum_q S_q^2 across groups (xor 8,16,32 spans one lane/group)
  float sq = s * s;
  #pragma unroll
  for (int d = 8; d < 64; d <<= 1) sq += __shfl_xor(sq, d, 64);
  const float rs = rsqrtf(sq);
  if ((lane & 7) == 0) x[(size_t)m2*8 + q] = s * rs;
}

// ---------------------------------------------------------------- fused MLP
// 48-row tiles (LDS 48KB -> 3 blocks/CU). Operand-swapped MFMA (acc = D[n][m]),
// two-plane f16 activations, 8-granule XOR swizzle.
// NOTE (r10 post-mortem): manual B-register pipelining / fused tails cause
// scratch spills. Keep register-lean (72 VGPR): best measured 106 us, MfmaUtil 53%.
#define SWX(r, c) ((r)*256 + ((c) ^ (((r)&7)<<3)))

__launch_bounds__(256, 3)
__global__ void k_mlp(const float* __restrict__ x, const f16* __restrict__ wfr12,
                      const f16* __restrict__ wfr0, const f16* __restrict__ wfr3,
                      const float* __restrict__ bias0, const float* __restrict__ bias1,
                      const float* __restrict__ bias2, const float* __restrict__ bias3,
                      float* __restrict__ y)
{
  __shared__ __align__(16) f16 xah[48*256];   // 24 KiB
  __shared__ __align__(16) f16 xal[48*256];   // 24 KiB
  const int tid = threadIdx.x, blk = blockIdx.x;
  const int lane = tid & 63, wv = tid >> 6;
  const int l15 = lane & 15, lh = lane >> 4;
  const int colb = wv*64;

  f32x4 acc[3][4];
  f16x8 ah[3], al[3], bh[4], bl[4];

  auto EPI = [&](){   // relu + exact f16 split + two-plane b64 swizzled writes
    #pragma unroll
    for (int Mt = 0; Mt < 3; ++Mt)
      #pragma unroll
      for (int nt = 0; nt < 4; ++nt){
        f16x4 h4, l4;
        #pragma unroll
        for (int r = 0; r < 4; ++r){
          const float v = fmaxf(acc[Mt][nt][r], 0.f);
          const f16 h = (f16)v;
          h4[r] = h; l4[r] = (f16)(v - (float)h);
        }
        const int idx = SWX(Mt*16 + l15, colb + nt*16 + lh*4);
        *(f16x4*)(xah + idx) = h4;
        *(f16x4*)(xal + idx) = l4;
      }
  };

  // ---------- layer 0 (8 -> 256, K padded to 32; zero-padded W kills garbage k)
  #pragma unroll
  for (int nt = 0; nt < 4; ++nt){
    const f32x4 b4 = *(const f32x4*)(bias0 + colb + nt*16 + lh*4);
    #pragma unroll
    for (int Mt = 0; Mt < 3; ++Mt) acc[Mt][nt] = b4;
  }
  #pragma unroll
  for (int Mt = 0; Mt < 3; ++Mt){
    const int row = blk*48 + Mt*16 + l15;   // tail rows read stale ws (finite), discarded
    const float* xr = x + (size_t)row*8;
    const float4 v0 = *(const float4*)xr;
    const float4 v1 = *(const float4*)(xr+4);
    const float vv[8] = {v0.x,v0.y,v0.z,v0.w,v1.x,v1.y,v1.z,v1.w};
    #pragma unroll
    for (int e = 0; e < 8; ++e){
      const f16 h = (f16)vv[e];
      ah[Mt][e] = h; al[Mt][e] = (f16)(vv[e] - (float)h);
    }
  }
  #pragma unroll
  for (int nt = 0; nt < 4; ++nt){
    bh[nt] = *(const f16x8*)(wfr0 + (size_t)(wv*4+nt)*1024 + lane*8);
    bl[nt] = *(const f16x8*)(wfr0 + (size_t)(wv*4+nt)*1024 + 512 + lane*8);
  }
  #pragma unroll
  for (int Mt = 0; Mt < 3; ++Mt)
    #pragma unroll
    for (int nt = 0; nt < 4; ++nt){
      acc[Mt][nt] = MFMA16(bh[nt], ah[Mt], acc[Mt][nt], 0, 0, 0);
      acc[Mt][nt] = MFMA16(bh[nt], al[Mt], acc[Mt][nt], 0, 0, 0);
      acc[Mt][nt] = MFMA16(bl[nt], ah[Mt], acc[Mt][nt], 0, 0, 0);
    }
  EPI();
  __syncthreads();

  // ---------- layers 1,2 (256 -> 256)
  for (int L = 0; L < 2; ++L){
    const float* bs = L ? bias2 : bias1;
    #pragma unroll
    for (int nt = 0; nt < 4; ++nt){
      const f32x4 b4 = *(const f32x4*)(bs + colb + nt*16 + lh*4);
      #pragma unroll
      for (int Mt = 0; Mt < 3; ++Mt) acc[Mt][nt] = b4;
    }
    #pragma unroll 2
    for (int kt = 0; kt < 8; ++kt){
      #pragma unroll
      for (int Mt = 0; Mt < 3; ++Mt){
        const int idx = SWX(Mt*16 + l15, kt*32 + lh*8);
        ah[Mt] = *(const f16x8*)(xah + idx);
        al[Mt] = *(const f16x8*)(xal + idx);
      }
      #pragma unroll
      for (int nt = 0; nt < 4; ++nt){
        const size_t f = ((size_t)(L*128 + (wv*4+nt)*8 + kt))*1024;
        bh[nt] = *(const f16x8*)(wfr12 + f + lane*8);
        bl[nt] = *(const f16x8*)(wfr12 + f + 512 + lane*8);
      }
      #pragma unroll
      for (int Mt = 0; Mt < 3; ++Mt)
        #pragma unroll
        for (int nt = 0; nt < 4; ++nt){
          acc[Mt][nt] = MFMA16(bh[nt], ah[Mt], acc[Mt][nt], 0, 0, 0);
          acc[Mt][nt] = MFMA16(bh[nt], al[Mt], acc[Mt][nt], 0, 0, 0);
          acc[Mt][nt] = MFMA16(bl[nt], ah[Mt], acc[Mt][nt], 0, 0, 0);
        }
    }
    __syncthreads();   // all reads done before overwrite
    EPI();
    __syncthreads();
  }

  // ---------- layer 3 (256 -> 8, N padded to 16; zero-padded W cols)
  f32x4 a3[3];
  {
    f32x4 b4 = {0.f, 0.f, 0.f, 0.f};
    if (lh < 2) b4 = *(const f32x4*)(bias3 + lh*4);
    #pragma unroll
    for (int Mt = 0; Mt < 3; ++Mt) a3[Mt] = b4;
  }
  #pragma unroll 2
  for (int kt = 0; kt < 8; ++kt){
    #pragma unroll
    for (int Mt = 0; Mt < 3; ++Mt){
      const int idx = SWX(Mt*16 + l15, kt*32 + lh*8);
      ah[Mt] = *(const f16x8*)(xah + idx);
      al[Mt] = *(const f16x8*)(xal + idx);
    }
    const f16x8 b3h = *(const f16x8*)(wfr3 + (size_t)kt*1024 + lane*8);
    const f16x8 b3l = *(const f16x8*)(wfr3 + (size_t)kt*1024 + 512 + lane*8);
    #pragma unroll
    for (int Mt = 0; Mt < 3; ++Mt){
      a3[Mt] = MFMA16(b3h, ah[Mt], a3[Mt], 0, 0, 0);
      a3[Mt] = MFMA16(b3h, al[Mt], a3[Mt], 0, 0, 0);
      a3[Mt] = MFMA16(b3l, ah[Mt], a3[Mt], 0, 0, 0);
    }
  }
  if (lh < 2){
    #pragma unroll
    for (int Mt = 0; Mt < 3; ++Mt){
      const int row = blk*48 + Mt*16 + l15;
      if (row < M2N) *(f32x4*)(y + (size_t)row*8 + lh*4) = a3[Mt];
    }
  }
}

// ---------------------------------------------------------------- per-element algebra
struct Elem {
  C2 p[2][2], g[2][2], UW[2], d0, d1;
  float A0, A1, A2, c0, c1, c2, c3;
};
struct Coef { float A0, A1, A2, c0, c1, c2, c3; };

__device__ __forceinline__ void elem_core(const float* __restrict__ x,
                                          const float* __restrict__ y,
                                          int gid, Elem& E)
{
  const float4 xr = *(const float4*)(x + (size_t)gid*8);
  const float4 xi = *(const float4*)(x + (size_t)gid*8 + 4);
  C2 h[2][2];
  h[0][0].x = xr.x; h[0][0].y = xi.x; h[0][1].x = xr.y; h[0][1].y = xi.y;
  h[1][0].x = xr.z; h[1][0].y = xi.z; h[1][1].x = xr.w; h[1][1].y = xi.w;
  const float4 ya = *(const float4*)(y + (size_t)gid*8);
  const float4 yb = *(const float4*)(y + (size_t)gid*8 + 4);
  C2 U[2], Wm[2];
  U[0].x = ya.x; U[0].y = ya.z;  U[1].x = ya.y; U[1].y = ya.w;
  Wm[0].x = yb.x; Wm[0].y = yb.z; Wm[1].x = yb.y; Wm[1].y = yb.w;
  const float u20 = cabs2(U[0]), u21 = cabs2(U[1]);
  C2 cf[2];
  cf[0].x = Wm[0].x*u20; cf[0].y = Wm[0].y*u20;
  cf[1].x = Wm[1].x*u21; cf[1].y = Wm[1].y*u21;
  C2 B[2][2];
  #pragma unroll
  for (int i = 0; i < 2; ++i)
    #pragma unroll
    for (int j = 0; j < 2; ++j){
      const C2 t0 = cmul(conjc(h[0][i]), h[0][j]);
      const C2 t1 = cmul(conjc(h[1][i]), h[1][j]);
      B[i][j] = cadd(cmul(cf[0], t0), cmul(cf[1], t1));
    }
  C2 adj[2][2];
  adj[0][0] = B[1][1]; adj[0][1] = cneg(B[0][1]);
  adj[1][0] = cneg(B[1][0]); adj[1][1] = B[0][0];
  E.d0 = csub(cmul(B[0][0], B[1][1]), cmul(B[0][1], B[1][0]));
  E.d1.x = 2.f*(B[0][0].x + B[1][1].x);
  E.d1.y = 2.f*(B[0][0].y + B[1][1].y);
  #pragma unroll
  for (int k = 0; k < 2; ++k){
    #pragma unroll
    for (int j = 0; j < 2; ++j) E.g[k][j] = conjc(h[k][j]);
    #pragma unroll
    for (int i = 0; i < 2; ++i)
      E.p[k][i] = cadd(cmul(adj[i][0], E.g[k][0]), cmul(adj[i][1], E.g[k][1]));
    E.UW[k] = cmul(U[k], Wm[k]);
  }
  const float w0 = cabs2(E.UW[0]), w1 = cabs2(E.UW[1]);
  E.A0 = w0*(cabs2(E.p[0][0]) + cabs2(E.p[0][1])) + w1*(cabs2(E.p[1][0]) + cabs2(E.p[1][1]));
  E.A1 = 4.f*( w0*(dotr(E.p[0][0], E.g[0][0]) + dotr(E.p[0][1], E.g[0][1]))
             + w1*(dotr(E.p[1][0], E.g[1][0]) + dotr(E.p[1][1], E.g[1][1])) );
  E.A2 = 4.f*( w0*(cabs2(E.g[0][0]) + cabs2(E.g[0][1]))
             + w1*(cabs2(E.g[1][0]) + cabs2(E.g[1][1])) );
  E.c0 = cabs2(E.d0);
  E.c1 = 2.f*(E.d0.x*E.d1.x + E.d0.y*E.d1.y);
  E.c2 = cabs2(E.d1) + 8.f*E.d0.x;
  E.c3 = 8.f*E.d1.x;
}

// ---------------------------------------------------------------- bisection machinery
__device__ __forceinline__ float evalf(float mu, const Coef& C){
  const float num = C.A0 + mu*(C.A1 + mu*C.A2);
  const float den = C.c0 + mu*(C.c1 + mu*(C.c2 + mu*(C.c3 + mu*16.f)));
  return num/den;
}

__device__ __forceinline__ void replay(const float* __restrict__ slots, int nrounds,
                                       float& lo, float& hi)
{
  const int DP[4] = {5, 5, 5, 4};
  for (int r = 0; r < nrounds; ++r){
    const float lo0 = lo, span = hi - lo;
    int k = 0;
    for (int d = 0; d < DP[r]; ++d){
      const float sd = span * (1.0f / (float)(1 << (d+1)));
      const float mu = fmaf((float)(2*k + 1), sd, lo0);
      const bool big = slots[r*32 + (1 << d) - 1 + k] > 1.0f;
      lo = big ? mu : lo;
      hi = big ? hi : mu;
      k = 2*k + (big ? 1 : 0);
    }
  }
}

template<int D>
__device__ __forceinline__ void eval_round(const Coef& C, float lo, float hi,
                                           float* __restrict__ slots, int roundBase,
                                           float (*r4)[32])
{
  const int tid = threadIdx.x;
  const int lane = tid & 63, wv = tid >> 6;
  const float lo0 = lo, span = hi - lo;
  int node = 0;
  #pragma unroll
  for (int d = 0; d < D; ++d){
    const float sd = span * (1.0f / (float)(1 << (d+1)));
    for (int k = 0; k < (1 << d); ++k){
      const float mu = fmaf((float)(2*k + 1), sd, lo0);
      const float f = wred(evalf(mu, C));
      if (lane == 0) r4[wv][node] = f;
      ++node;
    }
  }
  __syncthreads();
  if (tid < (1 << D) - 1)
    atomicAdd(&slots[roundBase + tid], r4[0][tid] + r4[1][tid] + r4[2][tid] + r4[3][tid]);
}

// Round 0: fused coef computation (elem_core from x,y) + depth-5 eval.
__launch_bounds__(256)
__global__ void k_red0(const float* __restrict__ x, const float* __restrict__ y,
                       float* __restrict__ coef, float* __restrict__ slots)
{
  const int gid = blockIdx.x*256 + threadIdx.x;
  __shared__ float r4[4][32];
  Elem E;
  elem_core(x, y, gid, E);
  *(float4*)(coef + (size_t)gid*8)     = make_float4(E.A0, E.A1, E.A2, E.c0);
  *(float4*)(coef + (size_t)gid*8 + 4) = make_float4(E.c1, E.c2, E.c3, 0.f);
  Coef C; C.A0 = E.A0; C.A1 = E.A1; C.A2 = E.A2; C.c0 = E.c0;
  C.c1 = E.c1; C.c2 = E.c2; C.c3 = E.c3;
  eval_round<5>(C, 0.f, 10.f, slots, 0, r4);
}

// Rounds 1..3: LDS-cached slot replay + depth-D eval.
template<int ROUND, int D>
__launch_bounds__(256)
__global__ void k_red(const float* __restrict__ coef, float* __restrict__ slots)
{
  const int tid = threadIdx.x;
  const int gid = blockIdx.x*256 + tid;
  __shared__ float r4[4][32];
  __shared__ float sl[96];
  if (tid < ROUND*32) sl[tid] = slots[tid];

  const float4 a = *(const float4*)(coef + (size_t)gid*8);
  const float4 b = *(const float4*)(coef + (size_t)gid*8 + 4);
  Coef C; C.A0 = a.x; C.A1 = a.y; C.A2 = a.z; C.c0 = a.w;
  C.c1 = b.x; C.c2 = b.y; C.c3 = b.z;
  __syncthreads();

  float lo = 0.f, hi = 10.f;
  replay(sl, ROUND, lo, hi);
  eval_round<D>(C, lo, hi, slots, ROUND*32, r4);
}

// ---------------------------------------------------------------- output (+final V,Pm)
__global__ void k_out(const float* __restrict__ H, const float* __restrict__ x,
                      const float* __restrict__ y, const float2* __restrict__ g2,
                      const float* __restrict__ slots, float* __restrict__ out)
{
  const int b2 = blockIdx.x;
  const int tid = threadIdx.x;
  __shared__ float4 fs[64];
  __shared__ float Vs[32][8];
  __shared__ float scs[32];
  __shared__ float sl[128];

  if (tid >= 128) sl[tid - 128] = slots[tid - 128];
  if (tid < 64) fs[tid] = frf_inline(H, b2, tid);
  __syncthreads();

  if (tid < 64){
    const int n = tid & 31;
    const bool isP = tid >= 32;
    const int gid = isP ? (b2*32 + n) : (n*4096 + b2);
    float lo = 0.f, hi = 10.f;
    replay(sl, 4, lo, hi);
    const float mu = 0.5f*(lo + hi);   // 20th midpoint
    Elem E;
    elem_core(x, y, gid, E);
    C2 det; det.x = E.d0.x + mu*E.d1.x + 4.f*mu*mu; det.y = E.d0.y + mu*E.d1.y;
    const float id = 1.f/cabs2(det);
    C2 idet; idet.x = det.x*id; idet.y = -det.y*id;
    C2 Vv[2][2];
    #pragma unroll
    for (int k = 0; k < 2; ++k)
      #pragma unroll
      for (int i = 0; i < 2; ++i){
        C2 t; t.x = E.p[k][i].x + 2.f*mu*E.g[k][i].x; t.y = E.p[k][i].y + 2.f*mu*E.g[k][i].y;
        Vv[i][k] = cmul(E.UW[k], cmul(t, idet));
      }
    if (!isP){
      Vs[n][0] = Vv[0][0].x; Vs[n][1] = Vv[0][0].y;
      Vs[n][2] = Vv[0][1].x; Vs[n][3] = Vv[0][1].y;
      Vs[n][4] = Vv[1][0].x; Vs[n][5] = Vv[1][0].y;
      Vs[n][6] = Vv[1][1].x; Vs[n][7] = Vv[1][1].y;
    } else {
      const float2 gg2 = g2[gid & 4095];
      C2 gc; gc.x = gg2.x; gc.y = gg2.y;
      float P = 0.f;
      #pragma unroll
      for (int k = 0; k < 2; ++k){
        const C2 a = Vv[0][k], b = Vv[1][k];
        P += cabs2(a) + cabs2(b);
        const C2 t = cmul(gc, cmul(a, conjc(b)));
        P += 2.f*t.x;
      }
      scs[n] = 1.41421356237f * rsqrtf(P);
    }
  }
  __syncthreads();

  const int t = tid & 63;
  const int ng = tid >> 6;
  const float4 f = fs[t];
  C2 f0, f1; f0.x = f.x; f0.y = f.y; f1.x = f.z; f1.y = f.w;
  for (int n = ng; n < 32; n += 4){
    C2 M00, M01, M10, M11;
    M00.x = Vs[n][0]; M00.y = Vs[n][1]; M01.x = Vs[n][2]; M01.y = Vs[n][3];
    M10.x = Vs[n][4]; M10.y = Vs[n][5]; M11.x = Vs[n][6]; M11.y = Vs[n][7];
    const float sc = scs[n];
    const C2 c0 = cadd(cmul(f0, M00), cmul(f1, M10));
    const C2 c1 = cadd(cmul(f0, M01), cmul(f1, M11));
    const size_t base = (size_t)b2*8192 + n*128 + t*2;
    *(float2*)(out + base)        = make_float2(c0.x*sc, c1.x*sc);
    *(float2*)(out + base + 4096) = make_float2(c0.y*sc, c1.y*sc);
  }
}

// ---------------------------------------------------------------- launch
extern "C" void kernel_launch(void* const* d_in, const int* in_sizes, int n_in,
                              void* d_out, int out_size, void* d_ws, size_t ws_size,
                              hipStream_t stream)
{
  const float* H  = (const float*)d_in[0];
  const float* W0 = (const float*)d_in[1];
  const float* b0 = (const float*)d_in[2];
  const float* W1 = (const float*)d_in[3];
  const float* b1 = (const float*)d_in[4];
  const float* W2 = (const float*)d_in[5];
  const float* b2 = (const float*)d_in[6];
  const float* W3 = (const float*)d_in[7];
  const float* b3 = (const float*)d_in[8];
  float* out = (float*)d_out;
  char* ws = (char*)d_ws;
  (void)in_sizes; (void)n_in; (void)out_size; (void)ws_size;

  size_t o = 0;
  auto alloc = [&](size_t bytes) -> void* {
    void* p = ws + o;
    o += (bytes + 255) & ~(size_t)255;
    return p;
  };
  float2* g2    = (float2*)alloc((size_t)4096*sizeof(float2));      // 32 KiB
  float*  xbuf  = (float*) alloc((size_t)M2N*8*sizeof(float));      // 4 MiB
  float*  ybuf  = (float*) alloc((size_t)M2N*8*sizeof(float));      // 4 MiB
  float*  coef  = (float*) alloc((size_t)M2N*8*sizeof(float));      // 4 MiB
  float*  slots = (float*) alloc(256*sizeof(float));                // 1 KiB
  f16*    wfr12 = (f16*)   alloc((size_t)256*1024*sizeof(f16));     // 512 KiB
  f16*    wfr0  = (f16*)   alloc((size_t)16*1024*sizeof(f16));      // 32 KiB
  f16*    wfr3  = (f16*)   alloc((size_t)8*1024*sizeof(f16));       // 16 KiB

  k_prep<<<66, 256, 0, stream>>>(W0, W1, W2, W3, wfr12, wfr0, wfr3, slots);
  k_hequ<<<32768, 256, 0, stream>>>(H, xbuf, g2);
  k_mlp<<<2731, 256, 0, stream>>>(xbuf, wfr12, wfr0, wfr3, b0, b1, b2, b3, ybuf);
  k_red0<<<512, 256, 0, stream>>>(xbuf, ybuf, coef, slots);
  k_red<1,5><<<512, 256, 0, stream>>>(coef, slots);
  k_red<2,5><<<512, 256, 0, stream>>>(coef, slots);
  k_red<3,4><<<512, 256, 0, stream>>>(coef, slots);
  k_out<<<4096, 256, 0, stream>>>(H, xbuf, ybuf, g2, slots, out);
}